// Round 14
// baseline (433.144 us; speedup 1.0000x reference)
//
#include <hip/hip_runtime.h>

#define N_NODES 100000
#define N_EDGES 1600000
#define D 128
#define DE 32
#define SCAN_CHUNK 1024
#define N_CHUNKS ((N_NODES + SCAN_CHUNK - 1) / SCAN_CHUNK)  // 98
#define POS_BLOCKS (N_EDGES / 2 / 256)                      // 3125
#define XH_BLOCKS (N_NODES * D / 8 / 256)                   // 6250
#define EFH_BLOCKS (N_EDGES * DE / 8 / 256)                 // 25000

typedef int v4i __attribute__((ext_vector_type(4)));  // nt-load-legal int4

// NOTE on eps: reference divides by sqrt(deg_in*deg_out)+1e-10 with both
// degrees >= 1 -> the +1e-10 is ~1e-10 relative, far below f32 rounding.
// We factor w = ew * rsqrt(di) * rsqrt(do); rdo is uniform per dst-node, so
// rows accumulate with w' = ew*rdi[src] and scale by rdo once at the end.
//
// bf16 notes: x (R9) and ef (R13) are read as bf16 (RNE) with f32
// accumulation. Measured absmax with bf16-x: 0.0039 vs 0.019 threshold;
// bf16-ef adds ~0.003 through W_edge (row norm ~0.28).
//
// R11 lesson: do NOT route the 25.6MB rec stream through the scalar pipe
// (K$ misses serialize). Vector loads + shfl broadcasts win.
// R13: efh (102MB) + xh (25.6MB) both fit L3 -> random 64B-row over-fetch
// is recovered by neighbor-line L3 hits; rec gets nt-hints to not pollute.

__device__ inline float bflo(unsigned u) {
  return __uint_as_float(u << 16);
}
__device__ inline float bfhi(unsigned u) {
  return __uint_as_float(u & 0xFFFF0000u);
}
__device__ inline unsigned pk_bf2(float lo, float hi) {
  unsigned a = __float_as_uint(lo), b = __float_as_uint(hi);
  a = (a + 0x7FFFu + ((a >> 16) & 1)) >> 16;  // RNE
  b = (b + 0x7FFFu + ((b >> 16) & 1)) >> 16;
  return a | (b << 16);
}

// ---------------------------------------------------------------------------
// K1: zero deg replicas + cursor (contiguous 5N region).
__global__ __launch_bounds__(256) void init_kernel(int* __restrict__ z) {
  int idx = blockIdx.x * 256 + threadIdx.x;
  if (idx < 5 * N_NODES) z[idx] = 0;
}

// ---------------------------------------------------------------------------
// K2 (fused pre-pass): block ranges do
//   [0, POS)            : per-edge cursor atomics (2 edges/thr)
//   [POS, POS+XH)       : x -> bf16 table xh
//   [POS+XH, +EFH)      : ef -> bf16 table efh
// The BW-bound conversions overlap the atomic-latency-bound pos work.
__global__ __launch_bounds__(256) void pre_kernel(
    const int4* __restrict__ el2, int* __restrict__ cursor,
    int2* __restrict__ pos2, const float4* __restrict__ x4,
    uint4* __restrict__ xh4, const float4* __restrict__ ef4,
    uint4* __restrict__ efh4) {
  int b = blockIdx.x;
  if (b < POS_BLOCKS) {
    int i = b * 256 + threadIdx.x;  // edge-pair index
    if (i >= N_EDGES / 2) return;
    int4 e = el2[i];
    int2 p;
    p.x = atomicAdd(&cursor[e.y], 1);
    p.y = atomicAdd(&cursor[e.w], 1);
    pos2[i] = p;
  } else if (b < POS_BLOCKS + XH_BLOCKS) {
    int i = (b - POS_BLOCKS) * 256 + threadIdx.x;
    float4 f0 = x4[2 * i], f1 = x4[2 * i + 1];
    uint4 o;
    o.x = pk_bf2(f0.x, f0.y);
    o.y = pk_bf2(f0.z, f0.w);
    o.z = pk_bf2(f1.x, f1.y);
    o.w = pk_bf2(f1.z, f1.w);
    xh4[i] = o;
  } else {
    int i = (b - POS_BLOCKS - XH_BLOCKS) * 256 + threadIdx.x;
    float4 f0 = ef4[2 * i], f1 = ef4[2 * i + 1];
    uint4 o;
    o.x = pk_bf2(f0.x, f0.y);
    o.y = pk_bf2(f0.z, f0.w);
    o.z = pk_bf2(f1.x, f1.y);
    o.w = pk_bf2(f1.z, f1.w);
    efh4[i] = o;
  }
}

// ---------------------------------------------------------------------------
// K3a: per-1024-chunk exclusive scan of counts(=cursor) -> partial, totals.
__global__ __launch_bounds__(256) void scan1_kernel(
    const int* __restrict__ counts, int* __restrict__ partial,
    int* __restrict__ blocksum) {
  __shared__ int lds[256];
  int t = threadIdx.x;
  int base = blockIdx.x * SCAN_CHUNK + t * 4;
  int c[4];
  int s = 0;
#pragma unroll
  for (int k = 0; k < 4; k++) {
    c[k] = (base + k < N_NODES) ? counts[base + k] : 0;
    s += c[k];
  }
  lds[t] = s;
  __syncthreads();
  for (int off = 1; off < 256; off <<= 1) {
    int tmp = (t >= off) ? lds[t - off] : 0;
    __syncthreads();
    lds[t] += tmp;
    __syncthreads();
  }
  int run = lds[t] - s;
#pragma unroll
  for (int k = 0; k < 4; k++) {
    int v = base + k;
    if (v < N_NODES) partial[v] = run;
    run += c[k];
  }
  if (t == 255) blocksum[blockIdx.x] = lds[255];
}

// ---------------------------------------------------------------------------
// K3b: exclusive scan of the 98 chunk totals.
__global__ __launch_bounds__(128) void scan2_kernel(
    const int* __restrict__ blocksum, int* __restrict__ blockoff) {
  __shared__ int lds[128];
  int t = threadIdx.x;
  int v = (t < N_CHUNKS) ? blocksum[t] : 0;
  lds[t] = v;
  __syncthreads();
  for (int off = 1; off < 128; off <<= 1) {
    int tmp = (t >= off) ? lds[t - off] : 0;
    __syncthreads();
    lds[t] += tmp;
    __syncthreads();
  }
  if (t < N_CHUNKS) blockoff[t] = lds[t] - v;
}

// ---------------------------------------------------------------------------
// K4: place 16B AoS records {src, eid, ew, 0} at start[dst]+pos + deg_in
// replica atomics.
__global__ __launch_bounds__(256) void place_kernel(
    const int4* __restrict__ el2, const float2* __restrict__ ew2,
    const int2* __restrict__ pos2, const int* __restrict__ partial,
    const int* __restrict__ blockoff, float* __restrict__ deg4,
    int4* __restrict__ rec) {
  int i = blockIdx.x * 256 + threadIdx.x;  // edge-pair index
  if (i >= N_EDGES / 2) return;
  int4 e = el2[i];
  float2 w = ew2[i];
  int2 p = pos2[i];
  int r0 = (threadIdx.x & 3) * N_NODES;
  atomicAdd(&deg4[r0 + e.x], w.x);
  atomicAdd(&deg4[r0 + e.z], w.y);
  int4 rA, rB;
  rA.x = e.x; rA.y = 2 * i;     rA.z = __float_as_int(w.x); rA.w = 0;
  rB.x = e.z; rB.y = 2 * i + 1; rB.z = __float_as_int(w.y); rB.w = 0;
  rec[partial[e.y] + blockoff[e.y >> 10] + p.x] = rA;
  rec[partial[e.w] + blockoff[e.w >> 10] + p.y] = rB;
}

// ---------------------------------------------------------------------------
// K5: finalize rdi = rsqrt(1 + sum of 4 deg replicas).
__global__ __launch_bounds__(256) void rdi_kernel(
    const float* __restrict__ deg4, float* __restrict__ rdi) {
  int v = blockIdx.x * 256 + threadIdx.x;
  if (v >= N_NODES) return;
  rdi[v] = rsqrtf(1.f + deg4[v] + deg4[N_NODES + v] + deg4[2 * N_NODES + v] +
                  deg4[3 * N_NODES + v]);
}

// ---------------------------------------------------------------------------
// K6: single-pass fused gather (ef + x + row epilogue). One wave per node.
// Vector rec loads (nt: one-shot stream, keep L3 for xh/efh) + shfl
// broadcasts. Lane l accumulates dims 2l,2l+1 (one u32 = 2xbf16 per x-row);
// post-loop 4-shfl lane transpose restores the l/l+64 conflict-free
// epilogue. 8 edges/iter.
template <bool XH16, bool EF16>
__global__ __launch_bounds__(256) void gather_fused_kernel(
    const float* __restrict__ x, const ushort* __restrict__ xh,
    const float* __restrict__ ef, const ushort* __restrict__ efh,
    const int* __restrict__ partial, const int* __restrict__ blockoff,
    const int* __restrict__ counts, const int4* __restrict__ rec,
    const float* __restrict__ rdi, const float* __restrict__ W_edge,
    const float* __restrict__ b_edge, float* __restrict__ out) {
  __shared__ __align__(16) float we[128 * 36];
  __shared__ float beS[128];
  int t = threadIdx.x;
#pragma unroll
  for (int i = 0; i < 4; ++i) {  // 1024 float4 / 256 threads
    int f = t + i * 256;
    int r = f >> 3, kq = f & 7;
    *(float4*)&we[r * 36 + 4 * kq] = *(const float4*)&W_edge[r * DE + 4 * kq];
  }
  if (t < 128) beS[t] = b_edge[t];
  __syncthreads();

  int wid = t >> 6, lane = t & 63;
  int v = blockIdx.x * 4 + wid;
  if (v >= N_NODES) return;
  int start = partial[v] + blockoff[v >> 10];
  int cnt = counts[v];
  int lane31 = lane & 31;
  bool lowhalf = lane < 32;

  float A0 = 0.f, A1 = 0.f, B0 = 0.f, B1 = 0.f;
  float C0 = 0.f, C1 = 0.f, E0 = 0.f, E1 = 0.f;
  float ga = 0.f, gb = 0.f, gc = 0.f, gd = 0.f, dsum = 0.f, wsv = 0.f;

#define EFLOAD(eid) \
  (EF16 ? bflo((unsigned)efh[(size_t)(eid)*DE + lane31]) \
        : __builtin_nontemporal_load(&ef[(size_t)(eid)*DE + lane31]))

  for (int base = 0; base < cnt; base += 64) {
    int nb = cnt - base;
    if (nb > 64) nb = 64;
    int s_l = 0, e_l = 0;
    float w_l = 0.f;
    if (lane < nb) {
      v4i rv = __builtin_nontemporal_load(
          (const v4i*)&rec[start + base + lane]);
      s_l = rv.x;
      e_l = rv.y;
      float wraw = __int_as_float(rv.z);
      w_l = wraw * rdi[s_l];
      dsum += wraw;
      wsv += w_l;
    }
    int i = 0;
    for (; i + 8 <= nb; i += 8) {
      int s0 = __shfl(s_l, i + 0), s1 = __shfl(s_l, i + 1);
      int s2 = __shfl(s_l, i + 2), s3 = __shfl(s_l, i + 3);
      int s4 = __shfl(s_l, i + 4), s5 = __shfl(s_l, i + 5);
      int s6 = __shfl(s_l, i + 6), s7 = __shfl(s_l, i + 7);
      float w0 = __shfl(w_l, i + 0), w1 = __shfl(w_l, i + 1);
      float w2 = __shfl(w_l, i + 2), w3 = __shfl(w_l, i + 3);
      float w4 = __shfl(w_l, i + 4), w5 = __shfl(w_l, i + 5);
      float w6 = __shfl(w_l, i + 6), w7 = __shfl(w_l, i + 7);
      // ef: 4 half-wave loads; weights reuse w0..w7 via select
      int hh = lane >> 5;
      int eA = __shfl(e_l, i + 0 + hh), eB = __shfl(e_l, i + 2 + hh);
      int eC = __shfl(e_l, i + 4 + hh), eD = __shfl(e_l, i + 6 + hh);
      float wA = lowhalf ? w0 : w1, wB = lowhalf ? w2 : w3;
      float wC = lowhalf ? w4 : w5, wD = lowhalf ? w6 : w7;
      ga = fmaf(wA, EFLOAD(eA), ga);
      gb = fmaf(wB, EFLOAD(eB), gb);
      gc = fmaf(wC, EFLOAD(eC), gc);
      gd = fmaf(wD, EFLOAD(eD), gd);
      if (XH16) {
        unsigned u0 = ((const unsigned*)(xh + (size_t)s0 * D))[lane];
        unsigned u1 = ((const unsigned*)(xh + (size_t)s1 * D))[lane];
        unsigned u2 = ((const unsigned*)(xh + (size_t)s2 * D))[lane];
        unsigned u3 = ((const unsigned*)(xh + (size_t)s3 * D))[lane];
        unsigned u4 = ((const unsigned*)(xh + (size_t)s4 * D))[lane];
        unsigned u5 = ((const unsigned*)(xh + (size_t)s5 * D))[lane];
        unsigned u6 = ((const unsigned*)(xh + (size_t)s6 * D))[lane];
        unsigned u7 = ((const unsigned*)(xh + (size_t)s7 * D))[lane];
        A0 = fmaf(w0, bflo(u0), A0); A1 = fmaf(w0, bfhi(u0), A1);
        B0 = fmaf(w1, bflo(u1), B0); B1 = fmaf(w1, bfhi(u1), B1);
        C0 = fmaf(w2, bflo(u2), C0); C1 = fmaf(w2, bfhi(u2), C1);
        E0 = fmaf(w3, bflo(u3), E0); E1 = fmaf(w3, bfhi(u3), E1);
        A0 = fmaf(w4, bflo(u4), A0); A1 = fmaf(w4, bfhi(u4), A1);
        B0 = fmaf(w5, bflo(u5), B0); B1 = fmaf(w5, bfhi(u5), B1);
        C0 = fmaf(w6, bflo(u6), C0); C1 = fmaf(w6, bfhi(u6), C1);
        E0 = fmaf(w7, bflo(u7), E0); E1 = fmaf(w7, bfhi(u7), E1);
      } else {
        float2 u0 = ((const float2*)(x + (size_t)s0 * D))[lane];
        float2 u1 = ((const float2*)(x + (size_t)s1 * D))[lane];
        float2 u2 = ((const float2*)(x + (size_t)s2 * D))[lane];
        float2 u3 = ((const float2*)(x + (size_t)s3 * D))[lane];
        float2 u4 = ((const float2*)(x + (size_t)s4 * D))[lane];
        float2 u5 = ((const float2*)(x + (size_t)s5 * D))[lane];
        float2 u6 = ((const float2*)(x + (size_t)s6 * D))[lane];
        float2 u7 = ((const float2*)(x + (size_t)s7 * D))[lane];
        A0 = fmaf(w0, u0.x, A0); A1 = fmaf(w0, u0.y, A1);
        B0 = fmaf(w1, u1.x, B0); B1 = fmaf(w1, u1.y, B1);
        C0 = fmaf(w2, u2.x, C0); C1 = fmaf(w2, u2.y, C1);
        E0 = fmaf(w3, u3.x, E0); E1 = fmaf(w3, u3.y, E1);
        A0 = fmaf(w4, u4.x, A0); A1 = fmaf(w4, u4.y, A1);
        B0 = fmaf(w5, u5.x, B0); B1 = fmaf(w5, u5.y, B1);
        C0 = fmaf(w6, u6.x, C0); C1 = fmaf(w6, u6.y, C1);
        E0 = fmaf(w7, u7.x, E0); E1 = fmaf(w7, u7.y, E1);
      }
    }
    for (; i + 2 <= nb; i += 2) {
      int s0 = __shfl(s_l, i), s1 = __shfl(s_l, i + 1);
      float w0 = __shfl(w_l, i), w1 = __shfl(w_l, i + 1);
      int eE = __shfl(e_l, i + (lane >> 5));
      float wE = lowhalf ? w0 : w1;
      ga = fmaf(wE, EFLOAD(eE), ga);
      if (XH16) {
        unsigned u0 = ((const unsigned*)(xh + (size_t)s0 * D))[lane];
        unsigned u1 = ((const unsigned*)(xh + (size_t)s1 * D))[lane];
        A0 = fmaf(w0, bflo(u0), A0); A1 = fmaf(w0, bfhi(u0), A1);
        B0 = fmaf(w1, bflo(u1), B0); B1 = fmaf(w1, bfhi(u1), B1);
      } else {
        float2 u0 = ((const float2*)(x + (size_t)s0 * D))[lane];
        float2 u1 = ((const float2*)(x + (size_t)s1 * D))[lane];
        A0 = fmaf(w0, u0.x, A0); A1 = fmaf(w0, u0.y, A1);
        B0 = fmaf(w1, u1.x, B0); B1 = fmaf(w1, u1.y, B1);
      }
    }
    if (i < nb) {
      int s0 = __shfl(s_l, i);
      float w0 = __shfl(w_l, i);
      int eA = __shfl(e_l, i);
      if (lowhalf) ga = fmaf(w0, EFLOAD(eA), ga);
      if (XH16) {
        unsigned u0 = ((const unsigned*)(xh + (size_t)s0 * D))[lane];
        A0 = fmaf(w0, bflo(u0), A0);
        A1 = fmaf(w0, bfhi(u0), A1);
      } else {
        float2 u0 = ((const float2*)(x + (size_t)s0 * D))[lane];
        A0 = fmaf(w0, u0.x, A0);
        A1 = fmaf(w0, u0.y, A1);
      }
    }
  }
#undef EFLOAD
  float a0 = (A0 + B0) + (C0 + E0);  // dim 2*lane
  float a1 = (A1 + B1) + (C1 + E1);  // dim 2*lane+1
#pragma unroll
  for (int off = 32; off; off >>= 1) {
    dsum += __shfl_xor(dsum, off);
    wsv += __shfl_xor(wsv, off);
  }
  float rdo = rsqrtf(1.f + dsum);
  float gk = (ga + gb) + (gc + gd);
  gk += __shfl(gk, (lane + 32) & 63);  // lanes 0..31 hold full g_k

  // lane transpose: (2l,2l+1) layout -> (l, l+64)
  int half = lane >> 1;
  float v0 = __shfl(a0, half), v1 = __shfl(a1, half);
  float accLo = (lane & 1) ? v1 : v0;  // dim = lane
  float q0 = __shfl(a0, 32 + half), q1 = __shfl(a1, 32 + half);
  float accHi = (lane & 1) ? q1 : q0;  // dim = lane + 64

  // epilogue (pre-rdo accumulation; one scale at the end)
  size_t ro = (size_t)v * D;
  float xs0, xs1;
  if (XH16) {
    xs0 = __uint_as_float((unsigned)xh[ro + lane] << 16);
    xs1 = __uint_as_float((unsigned)xh[ro + lane + 64] << 16);
  } else {
    xs0 = x[ro + lane];
    xs1 = x[ro + lane + 64];
  }
  float rdiv = rdi[v];
  float s0 = accLo + rdiv * xs0 + wsv * beS[lane];
  float s1 = accHi + rdiv * xs1 + wsv * beS[lane + 64];
#pragma unroll
  for (int kq = 0; kq < 8; ++kq) {
    float4 w0 = *(const float4*)&we[lane * 36 + 4 * kq];
    float4 w1 = *(const float4*)&we[(lane + 64) * 36 + 4 * kq];
    float g0 = __shfl(gk, 4 * kq);
    float g1 = __shfl(gk, 4 * kq + 1);
    float g2 = __shfl(gk, 4 * kq + 2);
    float g3 = __shfl(gk, 4 * kq + 3);
    s0 += g0 * w0.x + g1 * w0.y + g2 * w0.z + g3 * w0.w;
    s1 += g0 * w1.x + g1 * w1.y + g2 * w1.z + g3 * w1.w;
  }
  out[ro + lane] = rdo * s0;
  out[ro + lane + 64] = rdo * s1;
}

// ---------------------------------------------------------------------------
// K7: in-place per-128-row-tile SGEMM: out = relu(out @ W_lin^T + b_lin).
// __launch_bounds__(256,3) + rolled kq-loop + one-b-at-a-time keeps VGPR low
// (R7 failure: 256 VGPR, 8.8% occupancy).
__global__ __launch_bounds__(256, 3) void gemm2_kernel(
    const float* __restrict__ W_lin, const float* __restrict__ b_lin,
    float* __restrict__ out) {
  __shared__ __align__(16) float xs[128 * 32];
  __shared__ __align__(16) float wl[128 * 32];
  int t = threadIdx.x;
  int tn = t & 15, tm = t >> 4;
  int m0 = 4 * tm, n0 = 4 * tn;
  int vbase = blockIdx.x * 128;
  float acc[8][8] = {};

  for (int ks = 0; ks < D; ks += 32) {
    __syncthreads();
#pragma unroll
    for (int i = 0; i < 4; ++i) {
      int f = t + i * 256;
      int r = f >> 3, kq = f & 7;
      int sw = (4 * kq) ^ (4 * ((r >> 2) & 7));
      float4 xv = make_float4(0.f, 0.f, 0.f, 0.f);
      if (vbase + r < N_NODES)
        xv = *(const float4*)&out[(size_t)(vbase + r) * D + ks + 4 * kq];
      *(float4*)&xs[r * 32 + sw] = xv;
      *(float4*)&wl[r * 32 + sw] = *(const float4*)&W_lin[r * D + ks + 4 * kq];
    }
    __syncthreads();
#pragma unroll 1
    for (int kq = 0; kq < 8; ++kq) {
      int sa = (4 * kq) ^ (4 * (tm & 7));
      int sb = (4 * kq) ^ (4 * (tn & 7));
      float4 a[8];
#pragma unroll
      for (int i = 0; i < 4; ++i) {
        a[i] = *(const float4*)&xs[(m0 + i) * 32 + sa];
        a[4 + i] = *(const float4*)&xs[(m0 + 64 + i) * 32 + sa];
      }
#pragma unroll
      for (int j = 0; j < 8; ++j) {
        int rj = (j < 4) ? (n0 + j) : (n0 + 60 + j);
        float4 b = *(const float4*)&wl[rj * 32 + sb];
#pragma unroll
        for (int i = 0; i < 8; ++i) {
          acc[i][j] += a[i].x * b.x + a[i].y * b.y + a[i].z * b.z +
                       a[i].w * b.w;
        }
      }
    }
  }

  float bl[8];
#pragma unroll
  for (int j = 0; j < 4; ++j) {
    bl[j] = b_lin[n0 + j];
    bl[4 + j] = b_lin[n0 + 64 + j];
  }
#pragma unroll
  for (int i = 0; i < 8; ++i) {
    int m = vbase + m0 + (i < 4 ? i : 64 + i - 4);
    if (m >= N_NODES) continue;
    float4 o0, o1;
    o0.x = fmaxf(acc[i][0] + bl[0], 0.f);
    o0.y = fmaxf(acc[i][1] + bl[1], 0.f);
    o0.z = fmaxf(acc[i][2] + bl[2], 0.f);
    o0.w = fmaxf(acc[i][3] + bl[3], 0.f);
    o1.x = fmaxf(acc[i][4] + bl[4], 0.f);
    o1.y = fmaxf(acc[i][5] + bl[5], 0.f);
    o1.z = fmaxf(acc[i][6] + bl[6], 0.f);
    o1.w = fmaxf(acc[i][7] + bl[7], 0.f);
    *(float4*)&out[(size_t)m * D + n0] = o0;
    *(float4*)&out[(size_t)m * D + n0 + 64] = o1;
  }
}

// ---------------------------------------------------------------------------
extern "C" void kernel_launch(void* const* d_in, const int* in_sizes, int n_in,
                              void* d_out, int out_size, void* d_ws,
                              size_t ws_size, hipStream_t stream) {
  const float* x      = (const float*)d_in[0];
  const int*   el     = (const int*)d_in[1];
  const float* ew     = (const float*)d_in[2];
  const float* ef     = (const float*)d_in[3];
  const float* W_lin  = (const float*)d_in[4];
  const float* b_lin  = (const float*)d_in[5];
  const float* W_edge = (const float*)d_in[6];
  const float* b_edge = (const float*)d_in[7];

  float* outp = (float*)d_out;  // fused gather writes rows; gemm2 in place

  // workspace tiers: T2 rec+xh+efh (~163.3 MB), T1 rec+xh (~60.9 MB),
  // T0 rec only (~34.8 MB, pure f32 path).
  char* base = (char*)d_ws;
  size_t off = 0;
  int4* rec = (int4*)(base + off); off += (size_t)N_EDGES * 16;
  ushort* xh = nullptr;
  ushort* efh = nullptr;
  // probe T2
  {
    size_t tail = (size_t)N_EDGES * 4 + (size_t)4 * N_NODES * 4 +
                  (size_t)N_NODES * 4 * 3 + 1024;
    size_t o2 = off;
    ushort* xh2 = (ushort*)(base + o2); o2 += (size_t)N_NODES * D * 2;
    ushort* efh2 = (ushort*)(base + o2); o2 += (size_t)N_EDGES * DE * 2;
    if (ws_size >= o2 + tail) {
      xh = xh2;
      efh = efh2;
      off = o2;
    } else {
      size_t o1 = off;
      ushort* xh1 = (ushort*)(base + o1); o1 += (size_t)N_NODES * D * 2;
      if (ws_size >= o1 + tail) {
        xh = xh1;
        off = o1;
      }
    }
  }
  int*  pos      = (int*)(base + off);  off += (size_t)N_EDGES * 4;
  float* deg4    = (float*)(base + off); off += (size_t)4 * N_NODES * 4;
  int*  cursor   = (int*)(base + off);  off += (size_t)N_NODES * 4;
  int*  partial  = (int*)(base + off);  off += (size_t)N_NODES * 4;
  int*  blocksum = (int*)(base + off);  off += 512;
  int*  blockoff = (int*)(base + off);  off += 512;
  float* rdi     = (float*)(base + off); off += (size_t)N_NODES * 4;

  int preBlocks = POS_BLOCKS;
  if (xh) preBlocks += XH_BLOCKS;
  if (efh) preBlocks += EFH_BLOCKS;

  hipLaunchKernelGGL(init_kernel, dim3((5 * N_NODES + 255) / 256), dim3(256),
                     0, stream, (int*)deg4);
  hipLaunchKernelGGL(pre_kernel, dim3(preBlocks), dim3(256), 0, stream,
                     (const int4*)el, cursor, (int2*)pos, (const float4*)x,
                     (uint4*)xh, (const float4*)ef, (uint4*)efh);
  hipLaunchKernelGGL(scan1_kernel, dim3(N_CHUNKS), dim3(256), 0, stream,
                     cursor, partial, blocksum);
  hipLaunchKernelGGL(scan2_kernel, dim3(1), dim3(128), 0, stream, blocksum,
                     blockoff);
  hipLaunchKernelGGL(place_kernel, dim3((N_EDGES / 2 + 255) / 256), dim3(256),
                     0, stream, (const int4*)el, (const float2*)ew,
                     (const int2*)pos, partial, blockoff, deg4, rec);
  hipLaunchKernelGGL(rdi_kernel, dim3((N_NODES + 255) / 256), dim3(256), 0,
                     stream, deg4, rdi);
  if (xh && efh) {
    hipLaunchKernelGGL((gather_fused_kernel<true, true>),
                       dim3((N_NODES + 3) / 4), dim3(256), 0, stream, x, xh,
                       ef, efh, partial, blockoff, cursor, rec, rdi, W_edge,
                       b_edge, outp);
  } else if (xh) {
    hipLaunchKernelGGL((gather_fused_kernel<true, false>),
                       dim3((N_NODES + 3) / 4), dim3(256), 0, stream, x, xh,
                       ef, efh, partial, blockoff, cursor, rec, rdi, W_edge,
                       b_edge, outp);
  } else {
    hipLaunchKernelGGL((gather_fused_kernel<false, false>),
                       dim3((N_NODES + 3) / 4), dim3(256), 0, stream, x, xh,
                       ef, efh, partial, blockoff, cursor, rec, rdi, W_edge,
                       b_edge, outp);
  }
  hipLaunchKernelGGL(gemm2_kernel, dim3((N_NODES + 127) / 128), dim3(256), 0,
                     stream, W_lin, b_lin, outp);
}

// Round 15
// 401.476 us; speedup vs baseline: 1.0789x; 1.0789x over previous
//
#include <hip/hip_runtime.h>

#define N_NODES 100000
#define N_EDGES 1600000
#define D 128
#define DE 32
#define SCAN_CHUNK 1024
#define N_CHUNKS ((N_NODES + SCAN_CHUNK - 1) / SCAN_CHUNK)  // 98
#define POS_BLOCKS (N_EDGES / 2 / 256)                      // 3125
#define XH_BLOCKS (N_NODES * D / 8 / 256)                   // 6250

typedef int v4i __attribute__((ext_vector_type(4)));  // nt-load-legal int4

// NOTE on eps: reference divides by sqrt(deg_in*deg_out)+1e-10 with both
// degrees >= 1 -> the +1e-10 is ~1e-10 relative, far below f32 rounding.
// We factor w = ew * rsqrt(di) * rsqrt(do); rdo is uniform per dst-node, so
// rows accumulate with w' = ew*rdi[src] and scale by rdo once at the end.
//
// bf16 note (R9): neighbor-sum reads bf16(x) (RNE) with f32 accumulation;
// measured absmax 0.0039 (unchanged vs f32) vs 0.019 threshold.
//
// R11 lesson: do NOT route the 25.6MB rec stream through the scalar pipe.
// R14 lesson: bf16-converting the one-shot ef stream (307MB round trip to
// save ~100MB random demand) is a net loss — convert only reused streams.
// R15: w' = ew*rdi[src] precomputed into rec.w (wrec pass) removes the
// random rdi load + mul from gather's short critical path.

__device__ inline float bflo(unsigned u) {
  return __uint_as_float(u << 16);
}
__device__ inline float bfhi(unsigned u) {
  return __uint_as_float(u & 0xFFFF0000u);
}
__device__ inline unsigned pk_bf2(float lo, float hi) {
  unsigned a = __float_as_uint(lo), b = __float_as_uint(hi);
  a = (a + 0x7FFFu + ((a >> 16) & 1)) >> 16;  // RNE
  b = (b + 0x7FFFu + ((b >> 16) & 1)) >> 16;
  return a | (b << 16);
}

// ---------------------------------------------------------------------------
// K1: zero deg replicas + cursor (contiguous 5N region).
__global__ __launch_bounds__(256) void init_kernel(int* __restrict__ z) {
  int idx = blockIdx.x * 256 + threadIdx.x;
  if (idx < 5 * N_NODES) z[idx] = 0;
}

// ---------------------------------------------------------------------------
// K2 (fused): blocks [0,POS_BLOCKS) do per-edge cursor atomics (2 edges/thr);
// remaining blocks convert x -> bf16 table xh (BW work overlaps atomic work).
__global__ __launch_bounds__(256) void pre_kernel(
    const int4* __restrict__ el2, int* __restrict__ cursor,
    int2* __restrict__ pos2, const float4* __restrict__ x4,
    uint4* __restrict__ xh4) {
  int b = blockIdx.x;
  if (b < POS_BLOCKS) {
    int i = b * 256 + threadIdx.x;  // edge-pair index
    if (i >= N_EDGES / 2) return;
    int4 e = el2[i];
    int2 p;
    p.x = atomicAdd(&cursor[e.y], 1);
    p.y = atomicAdd(&cursor[e.w], 1);
    pos2[i] = p;
  } else {
    int i = (b - POS_BLOCKS) * 256 + threadIdx.x;
    if (i >= N_NODES * D / 8) return;
    float4 f0 = x4[2 * i], f1 = x4[2 * i + 1];
    uint4 o;
    o.x = pk_bf2(f0.x, f0.y);
    o.y = pk_bf2(f0.z, f0.w);
    o.z = pk_bf2(f1.x, f1.y);
    o.w = pk_bf2(f1.z, f1.w);
    xh4[i] = o;
  }
}

// ---------------------------------------------------------------------------
// K3a: per-1024-chunk exclusive scan of counts(=cursor) -> partial, totals.
__global__ __launch_bounds__(256) void scan1_kernel(
    const int* __restrict__ counts, int* __restrict__ partial,
    int* __restrict__ blocksum) {
  __shared__ int lds[256];
  int t = threadIdx.x;
  int base = blockIdx.x * SCAN_CHUNK + t * 4;
  int c[4];
  int s = 0;
#pragma unroll
  for (int k = 0; k < 4; k++) {
    c[k] = (base + k < N_NODES) ? counts[base + k] : 0;
    s += c[k];
  }
  lds[t] = s;
  __syncthreads();
  for (int off = 1; off < 256; off <<= 1) {
    int tmp = (t >= off) ? lds[t - off] : 0;
    __syncthreads();
    lds[t] += tmp;
    __syncthreads();
  }
  int run = lds[t] - s;
#pragma unroll
  for (int k = 0; k < 4; k++) {
    int v = base + k;
    if (v < N_NODES) partial[v] = run;
    run += c[k];
  }
  if (t == 255) blocksum[blockIdx.x] = lds[255];
}

// ---------------------------------------------------------------------------
// K3b: exclusive scan of the 98 chunk totals.
__global__ __launch_bounds__(128) void scan2_kernel(
    const int* __restrict__ blocksum, int* __restrict__ blockoff) {
  __shared__ int lds[128];
  int t = threadIdx.x;
  int v = (t < N_CHUNKS) ? blocksum[t] : 0;
  lds[t] = v;
  __syncthreads();
  for (int off = 1; off < 128; off <<= 1) {
    int tmp = (t >= off) ? lds[t - off] : 0;
    __syncthreads();
    lds[t] += tmp;
    __syncthreads();
  }
  if (t < N_CHUNKS) blockoff[t] = lds[t] - v;
}

// ---------------------------------------------------------------------------
// K4: place 16B AoS records {src, eid, ew, 0} at start[dst]+pos + deg_in
// replica atomics.
__global__ __launch_bounds__(256) void place_kernel(
    const int4* __restrict__ el2, const float2* __restrict__ ew2,
    const int2* __restrict__ pos2, const int* __restrict__ partial,
    const int* __restrict__ blockoff, float* __restrict__ deg4,
    int4* __restrict__ rec) {
  int i = blockIdx.x * 256 + threadIdx.x;  // edge-pair index
  if (i >= N_EDGES / 2) return;
  int4 e = el2[i];
  float2 w = ew2[i];
  int2 p = pos2[i];
  int r0 = (threadIdx.x & 3) * N_NODES;
  atomicAdd(&deg4[r0 + e.x], w.x);
  atomicAdd(&deg4[r0 + e.z], w.y);
  int4 rA, rB;
  rA.x = e.x; rA.y = 2 * i;     rA.z = __float_as_int(w.x); rA.w = 0;
  rB.x = e.z; rB.y = 2 * i + 1; rB.z = __float_as_int(w.y); rB.w = 0;
  rec[partial[e.y] + blockoff[e.y >> 10] + p.x] = rA;
  rec[partial[e.w] + blockoff[e.w >> 10] + p.y] = rB;
}

// ---------------------------------------------------------------------------
// K5: finalize rdi = rsqrt(1 + sum of 4 deg replicas).
__global__ __launch_bounds__(256) void rdi_kernel(
    const float* __restrict__ deg4, float* __restrict__ rdi) {
  int v = blockIdx.x * 256 + threadIdx.x;
  if (v >= N_NODES) return;
  rdi[v] = rsqrtf(1.f + deg4[v] + deg4[N_NODES + v] + deg4[2 * N_NODES + v] +
                  deg4[3 * N_NODES + v]);
}

// ---------------------------------------------------------------------------
// K5b (R15): fold w' = ew*rdi[src] into rec.w so gather's batch load yields
// the final weight directly (no random rdi load / mul on the critical path).
__global__ __launch_bounds__(256) void wrec_kernel(
    int4* __restrict__ rec, const float* __restrict__ rdi) {
  int i = blockIdx.x * 256 + threadIdx.x;
  if (i >= N_EDGES) return;
  int4 r = rec[i];
  r.w = __float_as_int(__int_as_float(r.z) * rdi[r.x]);
  rec[i] = r;
}

// ---------------------------------------------------------------------------
// K6: single-pass fused gather (ef + x + row epilogue). One wave per node.
// Vector rec loads (nt: one-shot stream, keep L3 for xh) + shfl broadcasts.
// Lane l accumulates dims 2l,2l+1 (one u32 = 2xbf16 per x-row); post-loop
// 4-shfl lane transpose restores the l/l+64 conflict-free epilogue.
// 8 edges/iter.
template <bool XH16>
__global__ __launch_bounds__(256) void gather_fused_kernel(
    const float* __restrict__ x, const ushort* __restrict__ xh,
    const float* __restrict__ ef, const int* __restrict__ partial,
    const int* __restrict__ blockoff, const int* __restrict__ counts,
    const int4* __restrict__ rec, const float* __restrict__ rdi,
    const float* __restrict__ W_edge, const float* __restrict__ b_edge,
    float* __restrict__ out) {
  __shared__ __align__(16) float we[128 * 36];
  __shared__ float beS[128];
  int t = threadIdx.x;
#pragma unroll
  for (int i = 0; i < 4; ++i) {  // 1024 float4 / 256 threads
    int f = t + i * 256;
    int r = f >> 3, kq = f & 7;
    *(float4*)&we[r * 36 + 4 * kq] = *(const float4*)&W_edge[r * DE + 4 * kq];
  }
  if (t < 128) beS[t] = b_edge[t];
  __syncthreads();

  int wid = t >> 6, lane = t & 63;
  int v = blockIdx.x * 4 + wid;
  if (v >= N_NODES) return;
  int start = partial[v] + blockoff[v >> 10];
  int cnt = counts[v];
  int lane31 = lane & 31;
  bool lowhalf = lane < 32;

  float A0 = 0.f, A1 = 0.f, B0 = 0.f, B1 = 0.f;
  float C0 = 0.f, C1 = 0.f, E0 = 0.f, E1 = 0.f;
  float ga = 0.f, gb = 0.f, gc = 0.f, gd = 0.f, dsum = 0.f, wsv = 0.f;

#define EFLOAD(eid) __builtin_nontemporal_load(&ef[(size_t)(eid)*DE + lane31])

  for (int base = 0; base < cnt; base += 64) {
    int nb = cnt - base;
    if (nb > 64) nb = 64;
    int s_l = 0, e_l = 0;
    float w_l = 0.f;
    if (lane < nb) {
      v4i rv = __builtin_nontemporal_load(
          (const v4i*)&rec[start + base + lane]);
      s_l = rv.x;
      e_l = rv.y;
      dsum += __int_as_float(rv.z);
      w_l = __int_as_float(rv.w);  // precomputed ew*rdi[src] (wrec pass)
      wsv += w_l;
    }
    int i = 0;
    for (; i + 8 <= nb; i += 8) {
      int s0 = __shfl(s_l, i + 0), s1 = __shfl(s_l, i + 1);
      int s2 = __shfl(s_l, i + 2), s3 = __shfl(s_l, i + 3);
      int s4 = __shfl(s_l, i + 4), s5 = __shfl(s_l, i + 5);
      int s6 = __shfl(s_l, i + 6), s7 = __shfl(s_l, i + 7);
      float w0 = __shfl(w_l, i + 0), w1 = __shfl(w_l, i + 1);
      float w2 = __shfl(w_l, i + 2), w3 = __shfl(w_l, i + 3);
      float w4 = __shfl(w_l, i + 4), w5 = __shfl(w_l, i + 5);
      float w6 = __shfl(w_l, i + 6), w7 = __shfl(w_l, i + 7);
      // ef: 4 half-wave loads; weights reuse w0..w7 via select
      int hh = lane >> 5;
      int eA = __shfl(e_l, i + 0 + hh), eB = __shfl(e_l, i + 2 + hh);
      int eC = __shfl(e_l, i + 4 + hh), eD = __shfl(e_l, i + 6 + hh);
      float wA = lowhalf ? w0 : w1, wB = lowhalf ? w2 : w3;
      float wC = lowhalf ? w4 : w5, wD = lowhalf ? w6 : w7;
      ga = fmaf(wA, EFLOAD(eA), ga);
      gb = fmaf(wB, EFLOAD(eB), gb);
      gc = fmaf(wC, EFLOAD(eC), gc);
      gd = fmaf(wD, EFLOAD(eD), gd);
      if (XH16) {
        unsigned u0 = ((const unsigned*)(xh + (size_t)s0 * D))[lane];
        unsigned u1 = ((const unsigned*)(xh + (size_t)s1 * D))[lane];
        unsigned u2 = ((const unsigned*)(xh + (size_t)s2 * D))[lane];
        unsigned u3 = ((const unsigned*)(xh + (size_t)s3 * D))[lane];
        unsigned u4 = ((const unsigned*)(xh + (size_t)s4 * D))[lane];
        unsigned u5 = ((const unsigned*)(xh + (size_t)s5 * D))[lane];
        unsigned u6 = ((const unsigned*)(xh + (size_t)s6 * D))[lane];
        unsigned u7 = ((const unsigned*)(xh + (size_t)s7 * D))[lane];
        A0 = fmaf(w0, bflo(u0), A0); A1 = fmaf(w0, bfhi(u0), A1);
        B0 = fmaf(w1, bflo(u1), B0); B1 = fmaf(w1, bfhi(u1), B1);
        C0 = fmaf(w2, bflo(u2), C0); C1 = fmaf(w2, bfhi(u2), C1);
        E0 = fmaf(w3, bflo(u3), E0); E1 = fmaf(w3, bfhi(u3), E1);
        A0 = fmaf(w4, bflo(u4), A0); A1 = fmaf(w4, bfhi(u4), A1);
        B0 = fmaf(w5, bflo(u5), B0); B1 = fmaf(w5, bfhi(u5), B1);
        C0 = fmaf(w6, bflo(u6), C0); C1 = fmaf(w6, bfhi(u6), C1);
        E0 = fmaf(w7, bflo(u7), E0); E1 = fmaf(w7, bfhi(u7), E1);
      } else {
        float2 u0 = ((const float2*)(x + (size_t)s0 * D))[lane];
        float2 u1 = ((const float2*)(x + (size_t)s1 * D))[lane];
        float2 u2 = ((const float2*)(x + (size_t)s2 * D))[lane];
        float2 u3 = ((const float2*)(x + (size_t)s3 * D))[lane];
        float2 u4 = ((const float2*)(x + (size_t)s4 * D))[lane];
        float2 u5 = ((const float2*)(x + (size_t)s5 * D))[lane];
        float2 u6 = ((const float2*)(x + (size_t)s6 * D))[lane];
        float2 u7 = ((const float2*)(x + (size_t)s7 * D))[lane];
        A0 = fmaf(w0, u0.x, A0); A1 = fmaf(w0, u0.y, A1);
        B0 = fmaf(w1, u1.x, B0); B1 = fmaf(w1, u1.y, B1);
        C0 = fmaf(w2, u2.x, C0); C1 = fmaf(w2, u2.y, C1);
        E0 = fmaf(w3, u3.x, E0); E1 = fmaf(w3, u3.y, E1);
        A0 = fmaf(w4, u4.x, A0); A1 = fmaf(w4, u4.y, A1);
        B0 = fmaf(w5, u5.x, B0); B1 = fmaf(w5, u5.y, B1);
        C0 = fmaf(w6, u6.x, C0); C1 = fmaf(w6, u6.y, C1);
        E0 = fmaf(w7, u7.x, E0); E1 = fmaf(w7, u7.y, E1);
      }
    }
    for (; i + 2 <= nb; i += 2) {
      int s0 = __shfl(s_l, i), s1 = __shfl(s_l, i + 1);
      float w0 = __shfl(w_l, i), w1 = __shfl(w_l, i + 1);
      int eE = __shfl(e_l, i + (lane >> 5));
      float wE = lowhalf ? w0 : w1;
      ga = fmaf(wE, EFLOAD(eE), ga);
      if (XH16) {
        unsigned u0 = ((const unsigned*)(xh + (size_t)s0 * D))[lane];
        unsigned u1 = ((const unsigned*)(xh + (size_t)s1 * D))[lane];
        A0 = fmaf(w0, bflo(u0), A0); A1 = fmaf(w0, bfhi(u0), A1);
        B0 = fmaf(w1, bflo(u1), B0); B1 = fmaf(w1, bfhi(u1), B1);
      } else {
        float2 u0 = ((const float2*)(x + (size_t)s0 * D))[lane];
        float2 u1 = ((const float2*)(x + (size_t)s1 * D))[lane];
        A0 = fmaf(w0, u0.x, A0); A1 = fmaf(w0, u0.y, A1);
        B0 = fmaf(w1, u1.x, B0); B1 = fmaf(w1, u1.y, B1);
      }
    }
    if (i < nb) {
      int s0 = __shfl(s_l, i);
      float w0 = __shfl(w_l, i);
      int eA = __shfl(e_l, i);
      if (lowhalf) ga = fmaf(w0, EFLOAD(eA), ga);
      if (XH16) {
        unsigned u0 = ((const unsigned*)(xh + (size_t)s0 * D))[lane];
        A0 = fmaf(w0, bflo(u0), A0);
        A1 = fmaf(w0, bfhi(u0), A1);
      } else {
        float2 u0 = ((const float2*)(x + (size_t)s0 * D))[lane];
        A0 = fmaf(w0, u0.x, A0);
        A1 = fmaf(w0, u0.y, A1);
      }
    }
  }
#undef EFLOAD
  float a0 = (A0 + B0) + (C0 + E0);  // dim 2*lane
  float a1 = (A1 + B1) + (C1 + E1);  // dim 2*lane+1
#pragma unroll
  for (int off = 32; off; off >>= 1) {
    dsum += __shfl_xor(dsum, off);
    wsv += __shfl_xor(wsv, off);
  }
  float rdo = rsqrtf(1.f + dsum);
  float gk = (ga + gb) + (gc + gd);
  gk += __shfl(gk, (lane + 32) & 63);  // lanes 0..31 hold full g_k

  // lane transpose: (2l,2l+1) layout -> (l, l+64)
  int half = lane >> 1;
  float v0 = __shfl(a0, half), v1 = __shfl(a1, half);
  float accLo = (lane & 1) ? v1 : v0;  // dim = lane
  float q0 = __shfl(a0, 32 + half), q1 = __shfl(a1, 32 + half);
  float accHi = (lane & 1) ? q1 : q0;  // dim = lane + 64

  // epilogue (pre-rdo accumulation; one scale at the end)
  size_t ro = (size_t)v * D;
  float xs0, xs1;
  if (XH16) {
    xs0 = __uint_as_float((unsigned)xh[ro + lane] << 16);
    xs1 = __uint_as_float((unsigned)xh[ro + lane + 64] << 16);
  } else {
    xs0 = x[ro + lane];
    xs1 = x[ro + lane + 64];
  }
  float rdiv = rdi[v];
  float s0 = accLo + rdiv * xs0 + wsv * beS[lane];
  float s1 = accHi + rdiv * xs1 + wsv * beS[lane + 64];
#pragma unroll
  for (int kq = 0; kq < 8; ++kq) {
    float4 w0 = *(const float4*)&we[lane * 36 + 4 * kq];
    float4 w1 = *(const float4*)&we[(lane + 64) * 36 + 4 * kq];
    float g0 = __shfl(gk, 4 * kq);
    float g1 = __shfl(gk, 4 * kq + 1);
    float g2 = __shfl(gk, 4 * kq + 2);
    float g3 = __shfl(gk, 4 * kq + 3);
    s0 += g0 * w0.x + g1 * w0.y + g2 * w0.z + g3 * w0.w;
    s1 += g0 * w1.x + g1 * w1.y + g2 * w1.z + g3 * w1.w;
  }
  out[ro + lane] = rdo * s0;
  out[ro + lane + 64] = rdo * s1;
}

// ---------------------------------------------------------------------------
// K7: in-place per-128-row-tile SGEMM: out = relu(out @ W_lin^T + b_lin).
// __launch_bounds__(256,3) + rolled kq-loop + one-b-at-a-time keeps VGPR low
// (R7 failure: 256 VGPR, 8.8% occupancy).
__global__ __launch_bounds__(256, 3) void gemm2_kernel(
    const float* __restrict__ W_lin, const float* __restrict__ b_lin,
    float* __restrict__ out) {
  __shared__ __align__(16) float xs[128 * 32];
  __shared__ __align__(16) float wl[128 * 32];
  int t = threadIdx.x;
  int tn = t & 15, tm = t >> 4;
  int m0 = 4 * tm, n0 = 4 * tn;
  int vbase = blockIdx.x * 128;
  float acc[8][8] = {};

  for (int ks = 0; ks < D; ks += 32) {
    __syncthreads();
#pragma unroll
    for (int i = 0; i < 4; ++i) {
      int f = t + i * 256;
      int r = f >> 3, kq = f & 7;
      int sw = (4 * kq) ^ (4 * ((r >> 2) & 7));
      float4 xv = make_float4(0.f, 0.f, 0.f, 0.f);
      if (vbase + r < N_NODES)
        xv = *(const float4*)&out[(size_t)(vbase + r) * D + ks + 4 * kq];
      *(float4*)&xs[r * 32 + sw] = xv;
      *(float4*)&wl[r * 32 + sw] = *(const float4*)&W_lin[r * D + ks + 4 * kq];
    }
    __syncthreads();
#pragma unroll 1
    for (int kq = 0; kq < 8; ++kq) {
      int sa = (4 * kq) ^ (4 * (tm & 7));
      int sb = (4 * kq) ^ (4 * (tn & 7));
      float4 a[8];
#pragma unroll
      for (int i = 0; i < 4; ++i) {
        a[i] = *(const float4*)&xs[(m0 + i) * 32 + sa];
        a[4 + i] = *(const float4*)&xs[(m0 + 64 + i) * 32 + sa];
      }
#pragma unroll
      for (int j = 0; j < 8; ++j) {
        int rj = (j < 4) ? (n0 + j) : (n0 + 60 + j);
        float4 b = *(const float4*)&wl[rj * 32 + sb];
#pragma unroll
        for (int i = 0; i < 8; ++i) {
          acc[i][j] += a[i].x * b.x + a[i].y * b.y + a[i].z * b.z +
                       a[i].w * b.w;
        }
      }
    }
  }

  float bl[8];
#pragma unroll
  for (int j = 0; j < 4; ++j) {
    bl[j] = b_lin[n0 + j];
    bl[4 + j] = b_lin[n0 + 64 + j];
  }
#pragma unroll
  for (int i = 0; i < 8; ++i) {
    int m = vbase + m0 + (i < 4 ? i : 64 + i - 4);
    if (m >= N_NODES) continue;
    float4 o0, o1;
    o0.x = fmaxf(acc[i][0] + bl[0], 0.f);
    o0.y = fmaxf(acc[i][1] + bl[1], 0.f);
    o0.z = fmaxf(acc[i][2] + bl[2], 0.f);
    o0.w = fmaxf(acc[i][3] + bl[3], 0.f);
    o1.x = fmaxf(acc[i][4] + bl[4], 0.f);
    o1.y = fmaxf(acc[i][5] + bl[5], 0.f);
    o1.z = fmaxf(acc[i][6] + bl[6], 0.f);
    o1.w = fmaxf(acc[i][7] + bl[7], 0.f);
    *(float4*)&out[(size_t)m * D + n0] = o0;
    *(float4*)&out[(size_t)m * D + n0 + 64] = o1;
  }
}

// ---------------------------------------------------------------------------
extern "C" void kernel_launch(void* const* d_in, const int* in_sizes, int n_in,
                              void* d_out, int out_size, void* d_ws,
                              size_t ws_size, hipStream_t stream) {
  const float* x      = (const float*)d_in[0];
  const int*   el     = (const int*)d_in[1];
  const float* ew     = (const float*)d_in[2];
  const float* ef     = (const float*)d_in[3];
  const float* W_lin  = (const float*)d_in[4];
  const float* b_lin  = (const float*)d_in[5];
  const float* W_edge = (const float*)d_in[6];
  const float* b_edge = (const float*)d_in[7];

  float* outp = (float*)d_out;  // fused gather writes rows; gemm2 in place

  // workspace layout (~60.4 MB with xh; fallback ~34.8 MB without)
  char* base = (char*)d_ws;
  size_t off = 0;
  int4* rec      = (int4*)(base + off); off += (size_t)N_EDGES * 16;
  ushort* xh     = (ushort*)(base + off); off += (size_t)N_NODES * D * 2;
  int*  pos      = (int*)(base + off);  off += (size_t)N_EDGES * 4;
  float* deg4    = (float*)(base + off); off += (size_t)4 * N_NODES * 4;
  int*  cursor   = (int*)(base + off);  off += (size_t)N_NODES * 4;
  int*  partial  = (int*)(base + off);  off += (size_t)N_NODES * 4;
  int*  blocksum = (int*)(base + off);  off += 512;
  int*  blockoff = (int*)(base + off);  off += 512;
  float* rdi     = (float*)(base + off); off += (size_t)N_NODES * 4;
  const size_t REQ_FAST = off;
  bool fast = (ws_size >= REQ_FAST);
  if (!fast) {
    // fallback layout: drop xh, shift everything after it down 25.6MB
    off = (size_t)N_EDGES * 16;
    pos      = (int*)(base + off);  off += (size_t)N_EDGES * 4;
    deg4     = (float*)(base + off); off += (size_t)4 * N_NODES * 4;
    cursor   = (int*)(base + off);  off += (size_t)N_NODES * 4;
    partial  = (int*)(base + off);  off += (size_t)N_NODES * 4;
    blocksum = (int*)(base + off);  off += 512;
    blockoff = (int*)(base + off);  off += 512;
    rdi      = (float*)(base + off); off += (size_t)N_NODES * 4;
    xh       = nullptr;
  }

  hipLaunchKernelGGL(init_kernel, dim3((5 * N_NODES + 255) / 256), dim3(256),
                     0, stream, (int*)deg4);
  hipLaunchKernelGGL(pre_kernel, dim3(fast ? POS_BLOCKS + XH_BLOCKS
                                           : POS_BLOCKS),
                     dim3(256), 0, stream, (const int4*)el, cursor, (int2*)pos,
                     (const float4*)x, (uint4*)xh);
  hipLaunchKernelGGL(scan1_kernel, dim3(N_CHUNKS), dim3(256), 0, stream,
                     cursor, partial, blocksum);
  hipLaunchKernelGGL(scan2_kernel, dim3(1), dim3(128), 0, stream, blocksum,
                     blockoff);
  hipLaunchKernelGGL(place_kernel, dim3((N_EDGES / 2 + 255) / 256), dim3(256),
                     0, stream, (const int4*)el, (const float2*)ew,
                     (const int2*)pos, partial, blockoff, deg4, rec);
  hipLaunchKernelGGL(rdi_kernel, dim3((N_NODES + 255) / 256), dim3(256), 0,
                     stream, deg4, rdi);
  hipLaunchKernelGGL(wrec_kernel, dim3((N_EDGES + 255) / 256), dim3(256), 0,
                     stream, rec, rdi);
  if (fast) {
    hipLaunchKernelGGL(gather_fused_kernel<true>, dim3((N_NODES + 3) / 4),
                       dim3(256), 0, stream, x, xh, ef, partial, blockoff,
                       cursor, rec, rdi, W_edge, b_edge, outp);
  } else {
    hipLaunchKernelGGL(gather_fused_kernel<false>, dim3((N_NODES + 3) / 4),
                       dim3(256), 0, stream, x, xh, ef, partial, blockoff,
                       cursor, rec, rdi, W_edge, b_edge, outp);
  }
  hipLaunchKernelGGL(gemm2_kernel, dim3((N_NODES + 127) / 128), dim3(256), 0,
                     stream, W_lin, b_lin, outp);
}

// Round 16
// 356.125 us; speedup vs baseline: 1.2163x; 1.1273x over previous
//
#include <hip/hip_runtime.h>

#define N_NODES 100000
#define N_EDGES 1600000
#define D 128
#define DE 32
#define SCAN_CHUNK 1024
#define N_CHUNKS ((N_NODES + SCAN_CHUNK - 1) / SCAN_CHUNK)  // 98
#define POS_BLOCKS (N_EDGES / 2 / 256)                      // 3125
#define XH_BLOCKS (N_NODES * D / 8 / 256)                   // 6250

typedef int v4i __attribute__((ext_vector_type(4)));     // nt-load-legal int4
typedef __attribute__((ext_vector_type(8))) short bf16x8;  // 8 bf16 = 4 VGPR
typedef __attribute__((ext_vector_type(4))) float f32x4;

// NOTE on eps: reference divides by sqrt(deg_in*deg_out)+1e-10 with both
// degrees >= 1 -> the +1e-10 is ~1e-10 relative, far below f32 rounding.
// We factor w = ew * rsqrt(di) * rsqrt(do); rdo is uniform per dst-node, so
// rows accumulate with w' = ew*rdi[src] and scale by rdo once at the end.
//
// bf16 notes: x gathered as bf16 (R9, absmax 0.0039 unchanged) and the final
// GEMM runs on MFMA with bf16 inputs (R16, adds <= ~0.004; threshold 0.019).
//
// R11 lesson: don't route the 25.6MB rec stream through the scalar pipe.
// R14 lesson: bf16-converting the one-shot ef stream is a net loss.
// R15 lesson: wrec (pre-materializing ew*rdi) costs more than it saves —
// the random rdi L2 load was already latency-hidden.

__device__ inline float bflo(unsigned u) {
  return __uint_as_float(u << 16);
}
__device__ inline float bfhi(unsigned u) {
  return __uint_as_float(u & 0xFFFF0000u);
}
__device__ inline unsigned pk_bf2(float lo, float hi) {
  unsigned a = __float_as_uint(lo), b = __float_as_uint(hi);
  a = (a + 0x7FFFu + ((a >> 16) & 1)) >> 16;  // RNE
  b = (b + 0x7FFFu + ((b >> 16) & 1)) >> 16;
  return a | (b << 16);
}

// ---------------------------------------------------------------------------
// K1: zero deg replicas + cursor (contiguous 5N region).
__global__ __launch_bounds__(256) void init_kernel(int* __restrict__ z) {
  int idx = blockIdx.x * 256 + threadIdx.x;
  if (idx < 5 * N_NODES) z[idx] = 0;
}

// ---------------------------------------------------------------------------
// K2 (fused): blocks [0,POS_BLOCKS) do per-edge cursor atomics (2 edges/thr);
// remaining blocks convert x -> bf16 table xh (BW work overlaps atomic work).
__global__ __launch_bounds__(256) void pre_kernel(
    const int4* __restrict__ el2, int* __restrict__ cursor,
    int2* __restrict__ pos2, const float4* __restrict__ x4,
    uint4* __restrict__ xh4) {
  int b = blockIdx.x;
  if (b < POS_BLOCKS) {
    int i = b * 256 + threadIdx.x;  // edge-pair index
    if (i >= N_EDGES / 2) return;
    int4 e = el2[i];
    int2 p;
    p.x = atomicAdd(&cursor[e.y], 1);
    p.y = atomicAdd(&cursor[e.w], 1);
    pos2[i] = p;
  } else {
    int i = (b - POS_BLOCKS) * 256 + threadIdx.x;
    if (i >= N_NODES * D / 8) return;
    float4 f0 = x4[2 * i], f1 = x4[2 * i + 1];
    uint4 o;
    o.x = pk_bf2(f0.x, f0.y);
    o.y = pk_bf2(f0.z, f0.w);
    o.z = pk_bf2(f1.x, f1.y);
    o.w = pk_bf2(f1.z, f1.w);
    xh4[i] = o;
  }
}

// ---------------------------------------------------------------------------
// K3a: per-1024-chunk exclusive scan of counts(=cursor) -> partial, totals.
__global__ __launch_bounds__(256) void scan1_kernel(
    const int* __restrict__ counts, int* __restrict__ partial,
    int* __restrict__ blocksum) {
  __shared__ int lds[256];
  int t = threadIdx.x;
  int base = blockIdx.x * SCAN_CHUNK + t * 4;
  int c[4];
  int s = 0;
#pragma unroll
  for (int k = 0; k < 4; k++) {
    c[k] = (base + k < N_NODES) ? counts[base + k] : 0;
    s += c[k];
  }
  lds[t] = s;
  __syncthreads();
  for (int off = 1; off < 256; off <<= 1) {
    int tmp = (t >= off) ? lds[t - off] : 0;
    __syncthreads();
    lds[t] += tmp;
    __syncthreads();
  }
  int run = lds[t] - s;
#pragma unroll
  for (int k = 0; k < 4; k++) {
    int v = base + k;
    if (v < N_NODES) partial[v] = run;
    run += c[k];
  }
  if (t == 255) blocksum[blockIdx.x] = lds[255];
}

// ---------------------------------------------------------------------------
// K3b: exclusive scan of the 98 chunk totals.
__global__ __launch_bounds__(128) void scan2_kernel(
    const int* __restrict__ blocksum, int* __restrict__ blockoff) {
  __shared__ int lds[128];
  int t = threadIdx.x;
  int v = (t < N_CHUNKS) ? blocksum[t] : 0;
  lds[t] = v;
  __syncthreads();
  for (int off = 1; off < 128; off <<= 1) {
    int tmp = (t >= off) ? lds[t - off] : 0;
    __syncthreads();
    lds[t] += tmp;
    __syncthreads();
  }
  if (t < N_CHUNKS) blockoff[t] = lds[t] - v;
}

// ---------------------------------------------------------------------------
// K4: place 16B AoS records {src, eid, ew, 0} at start[dst]+pos + deg_in
// replica atomics.
__global__ __launch_bounds__(256) void place_kernel(
    const int4* __restrict__ el2, const float2* __restrict__ ew2,
    const int2* __restrict__ pos2, const int* __restrict__ partial,
    const int* __restrict__ blockoff, float* __restrict__ deg4,
    int4* __restrict__ rec) {
  int i = blockIdx.x * 256 + threadIdx.x;  // edge-pair index
  if (i >= N_EDGES / 2) return;
  int4 e = el2[i];
  float2 w = ew2[i];
  int2 p = pos2[i];
  int r0 = (threadIdx.x & 3) * N_NODES;
  atomicAdd(&deg4[r0 + e.x], w.x);
  atomicAdd(&deg4[r0 + e.z], w.y);
  int4 rA, rB;
  rA.x = e.x; rA.y = 2 * i;     rA.z = __float_as_int(w.x); rA.w = 0;
  rB.x = e.z; rB.y = 2 * i + 1; rB.z = __float_as_int(w.y); rB.w = 0;
  rec[partial[e.y] + blockoff[e.y >> 10] + p.x] = rA;
  rec[partial[e.w] + blockoff[e.w >> 10] + p.y] = rB;
}

// ---------------------------------------------------------------------------
// K5: finalize rdi = rsqrt(1 + sum of 4 deg replicas).
__global__ __launch_bounds__(256) void rdi_kernel(
    const float* __restrict__ deg4, float* __restrict__ rdi) {
  int v = blockIdx.x * 256 + threadIdx.x;
  if (v >= N_NODES) return;
  rdi[v] = rsqrtf(1.f + deg4[v] + deg4[N_NODES + v] + deg4[2 * N_NODES + v] +
                  deg4[3 * N_NODES + v]);
}

// ---------------------------------------------------------------------------
// K6: single-pass fused gather (ef + x + row epilogue). One wave per node.
// Vector rec loads (nt: one-shot stream, keep L3 for xh) + shfl broadcasts.
// Lane l accumulates dims 2l,2l+1 (one u32 = 2xbf16 per x-row); post-loop
// 4-shfl lane transpose restores the l/l+64 conflict-free epilogue.
// 8 edges/iter.
template <bool XH16>
__global__ __launch_bounds__(256) void gather_fused_kernel(
    const float* __restrict__ x, const ushort* __restrict__ xh,
    const float* __restrict__ ef, const int* __restrict__ partial,
    const int* __restrict__ blockoff, const int* __restrict__ counts,
    const int4* __restrict__ rec, const float* __restrict__ rdi,
    const float* __restrict__ W_edge, const float* __restrict__ b_edge,
    float* __restrict__ out) {
  __shared__ __align__(16) float we[128 * 36];
  __shared__ float beS[128];
  int t = threadIdx.x;
#pragma unroll
  for (int i = 0; i < 4; ++i) {  // 1024 float4 / 256 threads
    int f = t + i * 256;
    int r = f >> 3, kq = f & 7;
    *(float4*)&we[r * 36 + 4 * kq] = *(const float4*)&W_edge[r * DE + 4 * kq];
  }
  if (t < 128) beS[t] = b_edge[t];
  __syncthreads();

  int wid = t >> 6, lane = t & 63;
  int v = blockIdx.x * 4 + wid;
  if (v >= N_NODES) return;
  int start = partial[v] + blockoff[v >> 10];
  int cnt = counts[v];
  int lane31 = lane & 31;
  bool lowhalf = lane < 32;

  float A0 = 0.f, A1 = 0.f, B0 = 0.f, B1 = 0.f;
  float C0 = 0.f, C1 = 0.f, E0 = 0.f, E1 = 0.f;
  float ga = 0.f, gb = 0.f, gc = 0.f, gd = 0.f, dsum = 0.f, wsv = 0.f;

#define EFLOAD(eid) __builtin_nontemporal_load(&ef[(size_t)(eid)*DE + lane31])

  for (int base = 0; base < cnt; base += 64) {
    int nb = cnt - base;
    if (nb > 64) nb = 64;
    int s_l = 0, e_l = 0;
    float w_l = 0.f;
    if (lane < nb) {
      v4i rv = __builtin_nontemporal_load(
          (const v4i*)&rec[start + base + lane]);
      s_l = rv.x;
      e_l = rv.y;
      float wraw = __int_as_float(rv.z);
      w_l = wraw * rdi[s_l];
      dsum += wraw;
      wsv += w_l;
    }
    int i = 0;
    for (; i + 8 <= nb; i += 8) {
      int s0 = __shfl(s_l, i + 0), s1 = __shfl(s_l, i + 1);
      int s2 = __shfl(s_l, i + 2), s3 = __shfl(s_l, i + 3);
      int s4 = __shfl(s_l, i + 4), s5 = __shfl(s_l, i + 5);
      int s6 = __shfl(s_l, i + 6), s7 = __shfl(s_l, i + 7);
      float w0 = __shfl(w_l, i + 0), w1 = __shfl(w_l, i + 1);
      float w2 = __shfl(w_l, i + 2), w3 = __shfl(w_l, i + 3);
      float w4 = __shfl(w_l, i + 4), w5 = __shfl(w_l, i + 5);
      float w6 = __shfl(w_l, i + 6), w7 = __shfl(w_l, i + 7);
      // ef: 4 half-wave loads; weights reuse w0..w7 via select
      int hh = lane >> 5;
      int eA = __shfl(e_l, i + 0 + hh), eB = __shfl(e_l, i + 2 + hh);
      int eC = __shfl(e_l, i + 4 + hh), eD = __shfl(e_l, i + 6 + hh);
      float wA = lowhalf ? w0 : w1, wB = lowhalf ? w2 : w3;
      float wC = lowhalf ? w4 : w5, wD = lowhalf ? w6 : w7;
      ga = fmaf(wA, EFLOAD(eA), ga);
      gb = fmaf(wB, EFLOAD(eB), gb);
      gc = fmaf(wC, EFLOAD(eC), gc);
      gd = fmaf(wD, EFLOAD(eD), gd);
      if (XH16) {
        unsigned u0 = ((const unsigned*)(xh + (size_t)s0 * D))[lane];
        unsigned u1 = ((const unsigned*)(xh + (size_t)s1 * D))[lane];
        unsigned u2 = ((const unsigned*)(xh + (size_t)s2 * D))[lane];
        unsigned u3 = ((const unsigned*)(xh + (size_t)s3 * D))[lane];
        unsigned u4 = ((const unsigned*)(xh + (size_t)s4 * D))[lane];
        unsigned u5 = ((const unsigned*)(xh + (size_t)s5 * D))[lane];
        unsigned u6 = ((const unsigned*)(xh + (size_t)s6 * D))[lane];
        unsigned u7 = ((const unsigned*)(xh + (size_t)s7 * D))[lane];
        A0 = fmaf(w0, bflo(u0), A0); A1 = fmaf(w0, bfhi(u0), A1);
        B0 = fmaf(w1, bflo(u1), B0); B1 = fmaf(w1, bfhi(u1), B1);
        C0 = fmaf(w2, bflo(u2), C0); C1 = fmaf(w2, bfhi(u2), C1);
        E0 = fmaf(w3, bflo(u3), E0); E1 = fmaf(w3, bfhi(u3), E1);
        A0 = fmaf(w4, bflo(u4), A0); A1 = fmaf(w4, bfhi(u4), A1);
        B0 = fmaf(w5, bflo(u5), B0); B1 = fmaf(w5, bfhi(u5), B1);
        C0 = fmaf(w6, bflo(u6), C0); C1 = fmaf(w6, bfhi(u6), C1);
        E0 = fmaf(w7, bflo(u7), E0); E1 = fmaf(w7, bfhi(u7), E1);
      } else {
        float2 u0 = ((const float2*)(x + (size_t)s0 * D))[lane];
        float2 u1 = ((const float2*)(x + (size_t)s1 * D))[lane];
        float2 u2 = ((const float2*)(x + (size_t)s2 * D))[lane];
        float2 u3 = ((const float2*)(x + (size_t)s3 * D))[lane];
        float2 u4 = ((const float2*)(x + (size_t)s4 * D))[lane];
        float2 u5 = ((const float2*)(x + (size_t)s5 * D))[lane];
        float2 u6 = ((const float2*)(x + (size_t)s6 * D))[lane];
        float2 u7 = ((const float2*)(x + (size_t)s7 * D))[lane];
        A0 = fmaf(w0, u0.x, A0); A1 = fmaf(w0, u0.y, A1);
        B0 = fmaf(w1, u1.x, B0); B1 = fmaf(w1, u1.y, B1);
        C0 = fmaf(w2, u2.x, C0); C1 = fmaf(w2, u2.y, C1);
        E0 = fmaf(w3, u3.x, E0); E1 = fmaf(w3, u3.y, E1);
        A0 = fmaf(w4, u4.x, A0); A1 = fmaf(w4, u4.y, A1);
        B0 = fmaf(w5, u5.x, B0); B1 = fmaf(w5, u5.y, B1);
        C0 = fmaf(w6, u6.x, C0); C1 = fmaf(w6, u6.y, C1);
        E0 = fmaf(w7, u7.x, E0); E1 = fmaf(w7, u7.y, E1);
      }
    }
    for (; i + 2 <= nb; i += 2) {
      int s0 = __shfl(s_l, i), s1 = __shfl(s_l, i + 1);
      float w0 = __shfl(w_l, i), w1 = __shfl(w_l, i + 1);
      int eE = __shfl(e_l, i + (lane >> 5));
      float wE = lowhalf ? w0 : w1;
      ga = fmaf(wE, EFLOAD(eE), ga);
      if (XH16) {
        unsigned u0 = ((const unsigned*)(xh + (size_t)s0 * D))[lane];
        unsigned u1 = ((const unsigned*)(xh + (size_t)s1 * D))[lane];
        A0 = fmaf(w0, bflo(u0), A0); A1 = fmaf(w0, bfhi(u0), A1);
        B0 = fmaf(w1, bflo(u1), B0); B1 = fmaf(w1, bfhi(u1), B1);
      } else {
        float2 u0 = ((const float2*)(x + (size_t)s0 * D))[lane];
        float2 u1 = ((const float2*)(x + (size_t)s1 * D))[lane];
        A0 = fmaf(w0, u0.x, A0); A1 = fmaf(w0, u0.y, A1);
        B0 = fmaf(w1, u1.x, B0); B1 = fmaf(w1, u1.y, B1);
      }
    }
    if (i < nb) {
      int s0 = __shfl(s_l, i);
      float w0 = __shfl(w_l, i);
      int eA = __shfl(e_l, i);
      if (lowhalf) ga = fmaf(w0, EFLOAD(eA), ga);
      if (XH16) {
        unsigned u0 = ((const unsigned*)(xh + (size_t)s0 * D))[lane];
        A0 = fmaf(w0, bflo(u0), A0);
        A1 = fmaf(w0, bfhi(u0), A1);
      } else {
        float2 u0 = ((const float2*)(x + (size_t)s0 * D))[lane];
        A0 = fmaf(w0, u0.x, A0);
        A1 = fmaf(w0, u0.y, A1);
      }
    }
  }
#undef EFLOAD
  float a0 = (A0 + B0) + (C0 + E0);  // dim 2*lane
  float a1 = (A1 + B1) + (C1 + E1);  // dim 2*lane+1
#pragma unroll
  for (int off = 32; off; off >>= 1) {
    dsum += __shfl_xor(dsum, off);
    wsv += __shfl_xor(wsv, off);
  }
  float rdo = rsqrtf(1.f + dsum);
  float gk = (ga + gb) + (gc + gd);
  gk += __shfl(gk, (lane + 32) & 63);  // lanes 0..31 hold full g_k

  // lane transpose: (2l,2l+1) layout -> (l, l+64)
  int half = lane >> 1;
  float v0 = __shfl(a0, half), v1 = __shfl(a1, half);
  float accLo = (lane & 1) ? v1 : v0;  // dim = lane
  float q0 = __shfl(a0, 32 + half), q1 = __shfl(a1, 32 + half);
  float accHi = (lane & 1) ? q1 : q0;  // dim = lane + 64

  // epilogue (pre-rdo accumulation; one scale at the end)
  size_t ro = (size_t)v * D;
  float xs0, xs1;
  if (XH16) {
    xs0 = __uint_as_float((unsigned)xh[ro + lane] << 16);
    xs1 = __uint_as_float((unsigned)xh[ro + lane + 64] << 16);
  } else {
    xs0 = x[ro + lane];
    xs1 = x[ro + lane + 64];
  }
  float rdiv = rdi[v];
  float s0 = accLo + rdiv * xs0 + wsv * beS[lane];
  float s1 = accHi + rdiv * xs1 + wsv * beS[lane + 64];
#pragma unroll
  for (int kq = 0; kq < 8; ++kq) {
    float4 w0 = *(const float4*)&we[lane * 36 + 4 * kq];
    float4 w1 = *(const float4*)&we[(lane + 64) * 36 + 4 * kq];
    float g0 = __shfl(gk, 4 * kq);
    float g1 = __shfl(gk, 4 * kq + 1);
    float g2 = __shfl(gk, 4 * kq + 2);
    float g3 = __shfl(gk, 4 * kq + 3);
    s0 += g0 * w0.x + g1 * w0.y + g2 * w0.z + g3 * w0.w;
    s1 += g0 * w1.x + g1 * w1.y + g2 * w1.z + g3 * w1.w;
  }
  out[ro + lane] = rdo * s0;
  out[ro + lane + 64] = rdo * s1;
}

// ---------------------------------------------------------------------------
// K7 (R16): in-place MFMA GEMM: out = relu(out @ W_lin^T + b_lin), bf16
// inputs, f32 accumulate. Per block: 128 rows x 128 cols, K in 4 steps of 32.
// LDS: A-slice [128][40] bf16 (16B-aligned b128 frags, 2-way banks = free),
// W full [128][132] bf16 (2x b64 frags). 4 waves; wave w owns rows
// [32w,32w+32): 2 m-tiles x 8 n-tiles of 16x16x32 MFMA.
// Fragment layouts (guide-verified): A/B lane&15 = row(col), k=(lane>>4)*8+j;
// C/D col=lane&15, row=(lane>>4)*4+reg.
__global__ __launch_bounds__(256) void gemm2_mfma_kernel(
    const float* __restrict__ W_lin, const float* __restrict__ b_lin,
    float* __restrict__ out) {
  __shared__ __align__(16) ushort Asb[128 * 40];   // 10240 B
  __shared__ __align__(16) ushort Wsb[128 * 132];  // 33792 B
  int t = threadIdx.x;
  int vbase = blockIdx.x * 128;

  // stage W once (4096 float4 / 256 threads)
#pragma unroll
  for (int i = 0; i < 16; ++i) {
    int idx = t + i * 256;   // 0..4095
    int r = idx >> 5;        // 0..127
    int c = (idx & 31) * 4;  // 0..124
    float4 f = *(const float4*)&W_lin[r * D + c];
    uint2 u;
    u.x = pk_bf2(f.x, f.y);
    u.y = pk_bf2(f.z, f.w);
    *(uint2*)&Wsb[r * 132 + c] = u;
  }

  int lane = t & 63, w = t >> 6;
  int l15 = lane & 15, kg = lane >> 4;
  f32x4 acc[2][8] = {};

  for (int ks = 0; ks < 4; ++ks) {
    __syncthreads();  // protects Asb reuse (and W staging on first iter)
    // stage A slice [128][32] f32 -> bf16
#pragma unroll
    for (int i = 0; i < 4; ++i) {
      int idx = t + i * 256;  // 0..1023
      int r = idx >> 3;
      int c = (idx & 7) * 4;
      float4 f = make_float4(0.f, 0.f, 0.f, 0.f);
      if (vbase + r < N_NODES)
        f = *(const float4*)&out[(size_t)(vbase + r) * D + ks * 32 + c];
      uint2 u;
      u.x = pk_bf2(f.x, f.y);
      u.y = pk_bf2(f.z, f.w);
      *(uint2*)&Asb[r * 40 + c] = u;
    }
    __syncthreads();
    bf16x8 a0 = *(const bf16x8*)&Asb[(w * 32 + l15) * 40 + kg * 8];
    bf16x8 a1 = *(const bf16x8*)&Asb[(w * 32 + 16 + l15) * 40 + kg * 8];
#pragma unroll
    for (int nt = 0; nt < 8; ++nt) {
      const ushort* bp = &Wsb[(nt * 16 + l15) * 132 + ks * 32 + kg * 8];
      uint2 q0 = *(const uint2*)bp;
      uint2 q1 = *(const uint2*)(bp + 4);
      uint4 bu = make_uint4(q0.x, q0.y, q1.x, q1.y);
      bf16x8 bf = *(bf16x8*)&bu;
      acc[0][nt] =
          __builtin_amdgcn_mfma_f32_16x16x32_bf16(a0, bf, acc[0][nt], 0, 0, 0);
      acc[1][nt] =
          __builtin_amdgcn_mfma_f32_16x16x32_bf16(a1, bf, acc[1][nt], 0, 0, 0);
    }
  }

  // epilogue: bias + relu, in-place store (block-local rows, post-K-loop)
#pragma unroll
  for (int nt = 0; nt < 8; ++nt) {
    int col = nt * 16 + l15;
    float bl = b_lin[col];
#pragma unroll
    for (int mt = 0; mt < 2; ++mt) {
#pragma unroll
      for (int j = 0; j < 4; ++j) {
        int row = vbase + w * 32 + mt * 16 + kg * 4 + j;
        if (row < N_NODES)
          out[(size_t)row * D + col] = fmaxf(acc[mt][nt][j] + bl, 0.f);
      }
    }
  }
}

// ---------------------------------------------------------------------------
extern "C" void kernel_launch(void* const* d_in, const int* in_sizes, int n_in,
                              void* d_out, int out_size, void* d_ws,
                              size_t ws_size, hipStream_t stream) {
  const float* x      = (const float*)d_in[0];
  const int*   el     = (const int*)d_in[1];
  const float* ew     = (const float*)d_in[2];
  const float* ef     = (const float*)d_in[3];
  const float* W_lin  = (const float*)d_in[4];
  const float* b_lin  = (const float*)d_in[5];
  const float* W_edge = (const float*)d_in[6];
  const float* b_edge = (const float*)d_in[7];

  float* outp = (float*)d_out;  // fused gather writes rows; gemm2 in place

  // workspace layout (~60.4 MB with xh; fallback ~34.8 MB without)
  char* base = (char*)d_ws;
  size_t off = 0;
  int4* rec      = (int4*)(base + off); off += (size_t)N_EDGES * 16;
  ushort* xh     = (ushort*)(base + off); off += (size_t)N_NODES * D * 2;
  int*  pos      = (int*)(base + off);  off += (size_t)N_EDGES * 4;
  float* deg4    = (float*)(base + off); off += (size_t)4 * N_NODES * 4;
  int*  cursor   = (int*)(base + off);  off += (size_t)N_NODES * 4;
  int*  partial  = (int*)(base + off);  off += (size_t)N_NODES * 4;
  int*  blocksum = (int*)(base + off);  off += 512;
  int*  blockoff = (int*)(base + off);  off += 512;
  float* rdi     = (float*)(base + off); off += (size_t)N_NODES * 4;
  const size_t REQ_FAST = off;
  bool fast = (ws_size >= REQ_FAST);
  if (!fast) {
    // fallback layout: drop xh, shift everything after it down 25.6MB
    off = (size_t)N_EDGES * 16;
    pos      = (int*)(base + off);  off += (size_t)N_EDGES * 4;
    deg4     = (float*)(base + off); off += (size_t)4 * N_NODES * 4;
    cursor   = (int*)(base + off);  off += (size_t)N_NODES * 4;
    partial  = (int*)(base + off);  off += (size_t)N_NODES * 4;
    blocksum = (int*)(base + off);  off += 512;
    blockoff = (int*)(base + off);  off += 512;
    rdi      = (float*)(base + off); off += (size_t)N_NODES * 4;
    xh       = nullptr;
  }

  hipLaunchKernelGGL(init_kernel, dim3((5 * N_NODES + 255) / 256), dim3(256),
                     0, stream, (int*)deg4);
  hipLaunchKernelGGL(pre_kernel, dim3(fast ? POS_BLOCKS + XH_BLOCKS
                                           : POS_BLOCKS),
                     dim3(256), 0, stream, (const int4*)el, cursor, (int2*)pos,
                     (const float4*)x, (uint4*)xh);
  hipLaunchKernelGGL(scan1_kernel, dim3(N_CHUNKS), dim3(256), 0, stream,
                     cursor, partial, blocksum);
  hipLaunchKernelGGL(scan2_kernel, dim3(1), dim3(128), 0, stream, blocksum,
                     blockoff);
  hipLaunchKernelGGL(place_kernel, dim3((N_EDGES / 2 + 255) / 256), dim3(256),
                     0, stream, (const int4*)el, (const float2*)ew,
                     (const int2*)pos, partial, blockoff, deg4, rec);
  hipLaunchKernelGGL(rdi_kernel, dim3((N_NODES + 255) / 256), dim3(256), 0,
                     stream, deg4, rdi);
  if (fast) {
    hipLaunchKernelGGL(gather_fused_kernel<true>, dim3((N_NODES + 3) / 4),
                       dim3(256), 0, stream, x, xh, ef, partial, blockoff,
                       cursor, rec, rdi, W_edge, b_edge, outp);
  } else {
    hipLaunchKernelGGL(gather_fused_kernel<false>, dim3((N_NODES + 3) / 4),
                       dim3(256), 0, stream, x, xh, ef, partial, blockoff,
                       cursor, rec, rdi, W_edge, b_edge, outp);
  }
  hipLaunchKernelGGL(gemm2_mfma_kernel, dim3((N_NODES + 127) / 128), dim3(256),
                     0, stream, W_lin, b_lin, outp);
}

// Round 17
// 342.338 us; speedup vs baseline: 1.2653x; 1.0403x over previous
//
#include <hip/hip_runtime.h>

#define N_NODES 100000
#define N_EDGES 1600000
#define D 128
#define DE 32
#define SCAN_CHUNK 1024
#define N_CHUNKS ((N_NODES + SCAN_CHUNK - 1) / SCAN_CHUNK)  // 98
#define POS_BLOCKS (N_EDGES / 2 / 256)                      // 3125
#define XH_BLOCKS (N_NODES * D / 8 / 256)                   // 6250

typedef int v4i __attribute__((ext_vector_type(4)));     // nt-load-legal int4
typedef __attribute__((ext_vector_type(8))) short bf16x8;  // 8 bf16 = 4 VGPR
typedef __attribute__((ext_vector_type(4))) float f32x4;

// Algebra (R17): out = relu(U @ Wl^T + bl) with
//   U = rdo*(raw + rdi*x) + rdo*g@We^T + rdo*wsv*be
// = relu( A' @ Wl^T + gs @ (Wl@We)^T + csc*(Wl@be) + bl ),
//   A' = rdo*(raw+rdi*x) [stored in out], gs = rdo*g, csc = rdo*wsv.
// Wcombo = Wl@We (128x32) and blbe = Wl@be are precomputed on device.
// This deletes gather's per-node 32x128 W_edge matvec (~50% of its instrs).
//
// bf16: x gathered as bf16 (R9); GEMM inputs bf16 (R16). absmax 0.0039 vs
// 0.019 threshold. R11: no scalar-pipe rec. R14: don't bf16 one-shot ef.
// R15: don't pre-materialize ew*rdi (latency-hidden already).

__device__ inline float bflo(unsigned u) {
  return __uint_as_float(u << 16);
}
__device__ inline float bfhi(unsigned u) {
  return __uint_as_float(u & 0xFFFF0000u);
}
__device__ inline unsigned pk_bf2(float lo, float hi) {
  unsigned a = __float_as_uint(lo), b = __float_as_uint(hi);
  a = (a + 0x7FFFu + ((a >> 16) & 1)) >> 16;  // RNE
  b = (b + 0x7FFFu + ((b >> 16) & 1)) >> 16;
  return a | (b << 16);
}

// ---------------------------------------------------------------------------
// K1: zero deg replicas + cursor (contiguous 5N region).
__global__ __launch_bounds__(256) void init_kernel(int* __restrict__ z) {
  int idx = blockIdx.x * 256 + threadIdx.x;
  if (idx < 5 * N_NODES) z[idx] = 0;
}

// ---------------------------------------------------------------------------
// K2 (fused): blocks [0,POS_BLOCKS) do per-edge cursor atomics (2 edges/thr);
// remaining blocks convert x -> bf16 table xh (BW work overlaps atomic work).
__global__ __launch_bounds__(256) void pre_kernel(
    const int4* __restrict__ el2, int* __restrict__ cursor,
    int2* __restrict__ pos2, const float4* __restrict__ x4,
    uint4* __restrict__ xh4) {
  int b = blockIdx.x;
  if (b < POS_BLOCKS) {
    int i = b * 256 + threadIdx.x;  // edge-pair index
    if (i >= N_EDGES / 2) return;
    int4 e = el2[i];
    int2 p;
    p.x = atomicAdd(&cursor[e.y], 1);
    p.y = atomicAdd(&cursor[e.w], 1);
    pos2[i] = p;
  } else {
    int i = (b - POS_BLOCKS) * 256 + threadIdx.x;
    if (i >= N_NODES * D / 8) return;
    float4 f0 = x4[2 * i], f1 = x4[2 * i + 1];
    uint4 o;
    o.x = pk_bf2(f0.x, f0.y);
    o.y = pk_bf2(f0.z, f0.w);
    o.z = pk_bf2(f1.x, f1.y);
    o.w = pk_bf2(f1.z, f1.w);
    xh4[i] = o;
  }
}

// ---------------------------------------------------------------------------
// K3a: per-1024-chunk exclusive scan of counts(=cursor) -> partial, totals.
__global__ __launch_bounds__(256) void scan1_kernel(
    const int* __restrict__ counts, int* __restrict__ partial,
    int* __restrict__ blocksum) {
  __shared__ int lds[256];
  int t = threadIdx.x;
  int base = blockIdx.x * SCAN_CHUNK + t * 4;
  int c[4];
  int s = 0;
#pragma unroll
  for (int k = 0; k < 4; k++) {
    c[k] = (base + k < N_NODES) ? counts[base + k] : 0;
    s += c[k];
  }
  lds[t] = s;
  __syncthreads();
  for (int off = 1; off < 256; off <<= 1) {
    int tmp = (t >= off) ? lds[t - off] : 0;
    __syncthreads();
    lds[t] += tmp;
    __syncthreads();
  }
  int run = lds[t] - s;
#pragma unroll
  for (int k = 0; k < 4; k++) {
    int v = base + k;
    if (v < N_NODES) partial[v] = run;
    run += c[k];
  }
  if (t == 255) blocksum[blockIdx.x] = lds[255];
}

// ---------------------------------------------------------------------------
// K3b: exclusive scan of the 98 chunk totals.
__global__ __launch_bounds__(128) void scan2_kernel(
    const int* __restrict__ blocksum, int* __restrict__ blockoff) {
  __shared__ int lds[128];
  int t = threadIdx.x;
  int v = (t < N_CHUNKS) ? blocksum[t] : 0;
  lds[t] = v;
  __syncthreads();
  for (int off = 1; off < 128; off <<= 1) {
    int tmp = (t >= off) ? lds[t - off] : 0;
    __syncthreads();
    lds[t] += tmp;
    __syncthreads();
  }
  if (t < N_CHUNKS) blockoff[t] = lds[t] - v;
}

// ---------------------------------------------------------------------------
// K4: place 16B AoS records {src, eid, ew, 0} at start[dst]+pos + deg_in
// replica atomics.
__global__ __launch_bounds__(256) void place_kernel(
    const int4* __restrict__ el2, const float2* __restrict__ ew2,
    const int2* __restrict__ pos2, const int* __restrict__ partial,
    const int* __restrict__ blockoff, float* __restrict__ deg4,
    int4* __restrict__ rec) {
  int i = blockIdx.x * 256 + threadIdx.x;  // edge-pair index
  if (i >= N_EDGES / 2) return;
  int4 e = el2[i];
  float2 w = ew2[i];
  int2 p = pos2[i];
  int r0 = (threadIdx.x & 3) * N_NODES;
  atomicAdd(&deg4[r0 + e.x], w.x);
  atomicAdd(&deg4[r0 + e.z], w.y);
  int4 rA, rB;
  rA.x = e.x; rA.y = 2 * i;     rA.z = __float_as_int(w.x); rA.w = 0;
  rB.x = e.z; rB.y = 2 * i + 1; rB.z = __float_as_int(w.y); rB.w = 0;
  rec[partial[e.y] + blockoff[e.y >> 10] + p.x] = rA;
  rec[partial[e.w] + blockoff[e.w >> 10] + p.y] = rB;
}

// ---------------------------------------------------------------------------
// K5: finalize rdi = rsqrt(1 + sum of 4 deg replicas).
__global__ __launch_bounds__(256) void rdi_kernel(
    const float* __restrict__ deg4, float* __restrict__ rdi) {
  int v = blockIdx.x * 256 + threadIdx.x;
  if (v >= N_NODES) return;
  rdi[v] = rsqrtf(1.f + deg4[v] + deg4[N_NODES + v] + deg4[2 * N_NODES + v] +
                  deg4[3 * N_NODES + v]);
}

// ---------------------------------------------------------------------------
// K5c (R17): Wcombo = W_lin @ W_edge (128x32); blbe = W_lin @ b_edge (128).
// 16 blocks x 256 threads, one thread per (j,k); block 0 also does blbe.
__global__ __launch_bounds__(256) void combo_kernel(
    const float* __restrict__ W_lin, const float* __restrict__ W_edge,
    const float* __restrict__ b_edge, float* __restrict__ wcombo,
    float* __restrict__ blbe) {
  int idx = blockIdx.x * 256 + threadIdx.x;
  int j = idx >> 5, k = idx & 31;
  float s = 0.f;
#pragma unroll 8
  for (int d = 0; d < D; ++d) s += W_lin[j * D + d] * W_edge[d * DE + k];
  wcombo[j * DE + k] = s;
  if (blockIdx.x == 0 && threadIdx.x < D) {
    int jj = threadIdx.x;
    float b = 0.f;
#pragma unroll 8
    for (int d = 0; d < D; ++d) b += W_lin[jj * D + d] * b_edge[d];
    blbe[jj] = b;
  }
}

// ---------------------------------------------------------------------------
// K6: single-pass fused gather. One wave per node, 8 edges/iter, nt rec
// loads + shfl broadcasts; lane l owns dims 2l,2l+1 (u32 = 2xbf16 per row).
// FUSEWE=true: legacy W_edge epilogue (fallback tiers).
// FUSEWE=false (R17): thin epilogue — natural-order float2 store of
// rdo*(raw + rdi*x); g/wsv handed to the MFMA GEMM via gs/csc.
template <bool XH16, bool FUSEWE>
__global__ __launch_bounds__(256) void gather_fused_kernel(
    const float* __restrict__ x, const ushort* __restrict__ xh,
    const float* __restrict__ ef, const int* __restrict__ partial,
    const int* __restrict__ blockoff, const int* __restrict__ counts,
    const int4* __restrict__ rec, const float* __restrict__ rdi,
    const float* __restrict__ W_edge, const float* __restrict__ b_edge,
    float* __restrict__ gs, float* __restrict__ csc,
    float* __restrict__ out) {
  __shared__ __align__(16) float we[FUSEWE ? 128 * 36 : 4];
  __shared__ float beS[FUSEWE ? 128 : 4];
  int t = threadIdx.x;
  if (FUSEWE) {
#pragma unroll
    for (int i = 0; i < 4; ++i) {  // 1024 float4 / 256 threads
      int f = t + i * 256;
      int r = f >> 3, kq = f & 7;
      *(float4*)&we[r * 36 + 4 * kq] =
          *(const float4*)&W_edge[r * DE + 4 * kq];
    }
    if (t < 128) beS[t] = b_edge[t];
    __syncthreads();
  }

  int wid = t >> 6, lane = t & 63;
  int v = blockIdx.x * 4 + wid;
  if (v >= N_NODES) return;
  int start = partial[v] + blockoff[v >> 10];
  int cnt = counts[v];
  int lane31 = lane & 31;
  bool lowhalf = lane < 32;

  float A0 = 0.f, A1 = 0.f, B0 = 0.f, B1 = 0.f;
  float C0 = 0.f, C1 = 0.f, E0 = 0.f, E1 = 0.f;
  float ga = 0.f, gb = 0.f, gc = 0.f, gd = 0.f, dsum = 0.f, wsv = 0.f;

#define EFLOAD(eid) __builtin_nontemporal_load(&ef[(size_t)(eid)*DE + lane31])

  for (int base = 0; base < cnt; base += 64) {
    int nb = cnt - base;
    if (nb > 64) nb = 64;
    int s_l = 0, e_l = 0;
    float w_l = 0.f;
    if (lane < nb) {
      v4i rv = __builtin_nontemporal_load(
          (const v4i*)&rec[start + base + lane]);
      s_l = rv.x;
      e_l = rv.y;
      float wraw = __int_as_float(rv.z);
      w_l = wraw * rdi[s_l];
      dsum += wraw;
      wsv += w_l;
    }
    int i = 0;
    for (; i + 8 <= nb; i += 8) {
      int s0 = __shfl(s_l, i + 0), s1 = __shfl(s_l, i + 1);
      int s2 = __shfl(s_l, i + 2), s3 = __shfl(s_l, i + 3);
      int s4 = __shfl(s_l, i + 4), s5 = __shfl(s_l, i + 5);
      int s6 = __shfl(s_l, i + 6), s7 = __shfl(s_l, i + 7);
      float w0 = __shfl(w_l, i + 0), w1 = __shfl(w_l, i + 1);
      float w2 = __shfl(w_l, i + 2), w3 = __shfl(w_l, i + 3);
      float w4 = __shfl(w_l, i + 4), w5 = __shfl(w_l, i + 5);
      float w6 = __shfl(w_l, i + 6), w7 = __shfl(w_l, i + 7);
      int hh = lane >> 5;
      int eA = __shfl(e_l, i + 0 + hh), eB = __shfl(e_l, i + 2 + hh);
      int eC = __shfl(e_l, i + 4 + hh), eD = __shfl(e_l, i + 6 + hh);
      float wA = lowhalf ? w0 : w1, wB = lowhalf ? w2 : w3;
      float wC = lowhalf ? w4 : w5, wD = lowhalf ? w6 : w7;
      ga = fmaf(wA, EFLOAD(eA), ga);
      gb = fmaf(wB, EFLOAD(eB), gb);
      gc = fmaf(wC, EFLOAD(eC), gc);
      gd = fmaf(wD, EFLOAD(eD), gd);
      if (XH16) {
        unsigned u0 = ((const unsigned*)(xh + (size_t)s0 * D))[lane];
        unsigned u1 = ((const unsigned*)(xh + (size_t)s1 * D))[lane];
        unsigned u2 = ((const unsigned*)(xh + (size_t)s2 * D))[lane];
        unsigned u3 = ((const unsigned*)(xh + (size_t)s3 * D))[lane];
        unsigned u4 = ((const unsigned*)(xh + (size_t)s4 * D))[lane];
        unsigned u5 = ((const unsigned*)(xh + (size_t)s5 * D))[lane];
        unsigned u6 = ((const unsigned*)(xh + (size_t)s6 * D))[lane];
        unsigned u7 = ((const unsigned*)(xh + (size_t)s7 * D))[lane];
        A0 = fmaf(w0, bflo(u0), A0); A1 = fmaf(w0, bfhi(u0), A1);
        B0 = fmaf(w1, bflo(u1), B0); B1 = fmaf(w1, bfhi(u1), B1);
        C0 = fmaf(w2, bflo(u2), C0); C1 = fmaf(w2, bfhi(u2), C1);
        E0 = fmaf(w3, bflo(u3), E0); E1 = fmaf(w3, bfhi(u3), E1);
        A0 = fmaf(w4, bflo(u4), A0); A1 = fmaf(w4, bfhi(u4), A1);
        B0 = fmaf(w5, bflo(u5), B0); B1 = fmaf(w5, bfhi(u5), B1);
        C0 = fmaf(w6, bflo(u6), C0); C1 = fmaf(w6, bfhi(u6), C1);
        E0 = fmaf(w7, bflo(u7), E0); E1 = fmaf(w7, bfhi(u7), E1);
      } else {
        float2 u0 = ((const float2*)(x + (size_t)s0 * D))[lane];
        float2 u1 = ((const float2*)(x + (size_t)s1 * D))[lane];
        float2 u2 = ((const float2*)(x + (size_t)s2 * D))[lane];
        float2 u3 = ((const float2*)(x + (size_t)s3 * D))[lane];
        float2 u4 = ((const float2*)(x + (size_t)s4 * D))[lane];
        float2 u5 = ((const float2*)(x + (size_t)s5 * D))[lane];
        float2 u6 = ((const float2*)(x + (size_t)s6 * D))[lane];
        float2 u7 = ((const float2*)(x + (size_t)s7 * D))[lane];
        A0 = fmaf(w0, u0.x, A0); A1 = fmaf(w0, u0.y, A1);
        B0 = fmaf(w1, u1.x, B0); B1 = fmaf(w1, u1.y, B1);
        C0 = fmaf(w2, u2.x, C0); C1 = fmaf(w2, u2.y, C1);
        E0 = fmaf(w3, u3.x, E0); E1 = fmaf(w3, u3.y, E1);
        A0 = fmaf(w4, u4.x, A0); A1 = fmaf(w4, u4.y, A1);
        B0 = fmaf(w5, u5.x, B0); B1 = fmaf(w5, u5.y, B1);
        C0 = fmaf(w6, u6.x, C0); C1 = fmaf(w6, u6.y, C1);
        E0 = fmaf(w7, u7.x, E0); E1 = fmaf(w7, u7.y, E1);
      }
    }
    for (; i + 2 <= nb; i += 2) {
      int s0 = __shfl(s_l, i), s1 = __shfl(s_l, i + 1);
      float w0 = __shfl(w_l, i), w1 = __shfl(w_l, i + 1);
      int eE = __shfl(e_l, i + (lane >> 5));
      float wE = lowhalf ? w0 : w1;
      ga = fmaf(wE, EFLOAD(eE), ga);
      if (XH16) {
        unsigned u0 = ((const unsigned*)(xh + (size_t)s0 * D))[lane];
        unsigned u1 = ((const unsigned*)(xh + (size_t)s1 * D))[lane];
        A0 = fmaf(w0, bflo(u0), A0); A1 = fmaf(w0, bfhi(u0), A1);
        B0 = fmaf(w1, bflo(u1), B0); B1 = fmaf(w1, bfhi(u1), B1);
      } else {
        float2 u0 = ((const float2*)(x + (size_t)s0 * D))[lane];
        float2 u1 = ((const float2*)(x + (size_t)s1 * D))[lane];
        A0 = fmaf(w0, u0.x, A0); A1 = fmaf(w0, u0.y, A1);
        B0 = fmaf(w1, u1.x, B0); B1 = fmaf(w1, u1.y, B1);
      }
    }
    if (i < nb) {
      int s0 = __shfl(s_l, i);
      float w0 = __shfl(w_l, i);
      int eA = __shfl(e_l, i);
      if (lowhalf) ga = fmaf(w0, EFLOAD(eA), ga);
      if (XH16) {
        unsigned u0 = ((const unsigned*)(xh + (size_t)s0 * D))[lane];
        A0 = fmaf(w0, bflo(u0), A0);
        A1 = fmaf(w0, bfhi(u0), A1);
      } else {
        float2 u0 = ((const float2*)(x + (size_t)s0 * D))[lane];
        A0 = fmaf(w0, u0.x, A0);
        A1 = fmaf(w0, u0.y, A1);
      }
    }
  }
#undef EFLOAD
  float a0 = (A0 + B0) + (C0 + E0);  // dim 2*lane
  float a1 = (A1 + B1) + (C1 + E1);  // dim 2*lane+1
#pragma unroll
  for (int off = 32; off; off >>= 1) {
    dsum += __shfl_xor(dsum, off);
    wsv += __shfl_xor(wsv, off);
  }
  float rdo = rsqrtf(1.f + dsum);
  float gk = (ga + gb) + (gc + gd);
  gk += __shfl(gk, (lane + 32) & 63);  // lanes 0..31 hold full g_k

  size_t ro = (size_t)v * D;
  float rdiv = rdi[v];

  if (!FUSEWE) {
    // R17 thin epilogue: natural dim order (2l, 2l+1) — no transpose.
    float xs0, xs1;
    if (XH16) {
      unsigned u = ((const unsigned*)(xh + ro))[lane];
      xs0 = bflo(u);
      xs1 = bfhi(u);
    } else {
      float2 u = ((const float2*)(x + ro))[lane];
      xs0 = u.x;
      xs1 = u.y;
    }
    float2 st;
    st.x = rdo * (a0 + rdiv * xs0);
    st.y = rdo * (a1 + rdiv * xs1);
    ((float2*)(out + ro))[lane] = st;
    if (lowhalf) gs[(size_t)v * DE + lane] = rdo * gk;
    if (lane == 0) csc[v] = rdo * wsv;
    return;
  }

  // legacy epilogue (fallback tiers): lane transpose + W_edge matvec
  int half = lane >> 1;
  float v0 = __shfl(a0, half), v1 = __shfl(a1, half);
  float accLo = (lane & 1) ? v1 : v0;  // dim = lane
  float q0 = __shfl(a0, 32 + half), q1 = __shfl(a1, 32 + half);
  float accHi = (lane & 1) ? q1 : q0;  // dim = lane + 64

  float xs0, xs1;
  if (XH16) {
    xs0 = __uint_as_float((unsigned)xh[ro + lane] << 16);
    xs1 = __uint_as_float((unsigned)xh[ro + lane + 64] << 16);
  } else {
    xs0 = x[ro + lane];
    xs1 = x[ro + lane + 64];
  }
  float s0 = accLo + rdiv * xs0 + wsv * beS[lane];
  float s1 = accHi + rdiv * xs1 + wsv * beS[lane + 64];
#pragma unroll
  for (int kq = 0; kq < 8; ++kq) {
    float4 w0 = *(const float4*)&we[lane * 36 + 4 * kq];
    float4 w1 = *(const float4*)&we[(lane + 64) * 36 + 4 * kq];
    float g0 = __shfl(gk, 4 * kq);
    float g1 = __shfl(gk, 4 * kq + 1);
    float g2 = __shfl(gk, 4 * kq + 2);
    float g3 = __shfl(gk, 4 * kq + 3);
    s0 += g0 * w0.x + g1 * w0.y + g2 * w0.z + g3 * w0.w;
    s1 += g0 * w1.x + g1 * w1.y + g2 * w1.z + g3 * w1.w;
  }
  out[ro + lane] = rdo * s0;
  out[ro + lane + 64] = rdo * s1;
}

// ---------------------------------------------------------------------------
// K7: in-place MFMA GEMM, bf16 inputs, f32 accumulate.
// EXT=false: out = relu(out @ Wl^T + bl)                       (K=128)
// EXT=true : out = relu(out @ Wl^T + gs @ Wcombo^T
//                        + csc*blbe + bl)                      (K=160)
// Per block: 128 rows; LDS A-slice [128][40] bf16, Wl [128][132] bf16,
// Wcombo [128][36] bf16. 4 waves x {2 m-tiles x 8 n-tiles} 16x16x32 MFMA.
template <bool EXT>
__global__ __launch_bounds__(256) void gemm2_mfma_kernel(
    const float* __restrict__ W_lin, const float* __restrict__ b_lin,
    const float* __restrict__ wcombo, const float* __restrict__ blbe,
    const float* __restrict__ gs, const float* __restrict__ csc,
    float* __restrict__ out) {
  __shared__ __align__(16) ushort Asb[128 * 40];   // 10240 B
  __shared__ __align__(16) ushort Wsb[128 * 132];  // 33792 B
  __shared__ __align__(16) ushort Csb[128 * 36];   //  9216 B
  int t = threadIdx.x;
  int vbase = blockIdx.x * 128;

  // stage W_lin once (4096 float4 / 256 threads)
#pragma unroll
  for (int i = 0; i < 16; ++i) {
    int idx = t + i * 256;
    int r = idx >> 5;
    int c = (idx & 31) * 4;
    float4 f = *(const float4*)&W_lin[r * D + c];
    uint2 u;
    u.x = pk_bf2(f.x, f.y);
    u.y = pk_bf2(f.z, f.w);
    *(uint2*)&Wsb[r * 132 + c] = u;
  }
  if (EXT) {
    // stage Wcombo (128x32)
#pragma unroll
    for (int i = 0; i < 4; ++i) {
      int idx = t + i * 256;  // 0..1023
      int r = idx >> 3;
      int c = (idx & 7) * 4;
      float4 f = *(const float4*)&wcombo[r * DE + c];
      uint2 u;
      u.x = pk_bf2(f.x, f.y);
      u.y = pk_bf2(f.z, f.w);
      *(uint2*)&Csb[r * 36 + c] = u;
    }
  }

  int lane = t & 63, w = t >> 6;
  int l15 = lane & 15, kg = lane >> 4;
  f32x4 acc[2][8] = {};

  const int KSTEPS = EXT ? 5 : 4;
  for (int ks = 0; ks < KSTEPS; ++ks) {
    __syncthreads();  // protects Asb reuse (and W staging on first iter)
#pragma unroll
    for (int i = 0; i < 4; ++i) {
      int idx = t + i * 256;  // 0..1023
      int r = idx >> 3;
      int c = (idx & 7) * 4;
      float4 f = make_float4(0.f, 0.f, 0.f, 0.f);
      if (vbase + r < N_NODES) {
        if (!EXT || ks < 4)
          f = *(const float4*)&out[(size_t)(vbase + r) * D + ks * 32 + c];
        else
          f = *(const float4*)&gs[(size_t)(vbase + r) * DE + c];
      }
      uint2 u;
      u.x = pk_bf2(f.x, f.y);
      u.y = pk_bf2(f.z, f.w);
      *(uint2*)&Asb[r * 40 + c] = u;
    }
    __syncthreads();
    bf16x8 a0 = *(const bf16x8*)&Asb[(w * 32 + l15) * 40 + kg * 8];
    bf16x8 a1 = *(const bf16x8*)&Asb[(w * 32 + 16 + l15) * 40 + kg * 8];
#pragma unroll
    for (int nt = 0; nt < 8; ++nt) {
      uint2 q0, q1;
      if (!EXT || ks < 4) {
        const ushort* bp = &Wsb[(nt * 16 + l15) * 132 + ks * 32 + kg * 8];
        q0 = *(const uint2*)bp;
        q1 = *(const uint2*)(bp + 4);
      } else {
        const ushort* bp = &Csb[(nt * 16 + l15) * 36 + kg * 8];
        q0 = *(const uint2*)bp;
        q1 = *(const uint2*)(bp + 4);
      }
      uint4 bu = make_uint4(q0.x, q0.y, q1.x, q1.y);
      bf16x8 bf = *(bf16x8*)&bu;
      acc[0][nt] =
          __builtin_amdgcn_mfma_f32_16x16x32_bf16(a0, bf, acc[0][nt], 0, 0, 0);
      acc[1][nt] =
          __builtin_amdgcn_mfma_f32_16x16x32_bf16(a1, bf, acc[1][nt], 0, 0, 0);
    }
  }

  // epilogue: bias (+ rank-1 csc*blbe if EXT) + relu, in-place store
#pragma unroll
  for (int nt = 0; nt < 8; ++nt) {
    int col = nt * 16 + l15;
    float bl = b_lin[col];
    float bb = EXT ? blbe[col] : 0.f;
#pragma unroll
    for (int mt = 0; mt < 2; ++mt) {
#pragma unroll
      for (int j = 0; j < 4; ++j) {
        int row = vbase + w * 32 + mt * 16 + kg * 4 + j;
        if (row < N_NODES) {
          float val = acc[mt][nt][j] + bl;
          if (EXT) val += csc[row] * bb;
          out[(size_t)row * D + col] = fmaxf(val, 0.f);
        }
      }
    }
  }
}

// ---------------------------------------------------------------------------
extern "C" void kernel_launch(void* const* d_in, const int* in_sizes, int n_in,
                              void* d_out, int out_size, void* d_ws,
                              size_t ws_size, hipStream_t stream) {
  const float* x      = (const float*)d_in[0];
  const int*   el     = (const int*)d_in[1];
  const float* ew     = (const float*)d_in[2];
  const float* ef     = (const float*)d_in[3];
  const float* W_lin  = (const float*)d_in[4];
  const float* b_lin  = (const float*)d_in[5];
  const float* W_edge = (const float*)d_in[6];
  const float* b_edge = (const float*)d_in[7];

  float* outp = (float*)d_out;

  // tiers: T2 (~73.6MB) thin-gather + K=160 GEMM; T1 (~60.4MB) = R16;
  // T0 (~34.8MB) f32 gather + K=128 GEMM.
  char* base = (char*)d_ws;
  size_t off = 0;
  int4* rec      = (int4*)(base + off); off += (size_t)N_EDGES * 16;
  ushort* xh     = (ushort*)(base + off); off += (size_t)N_NODES * D * 2;
  int*  pos      = (int*)(base + off);  off += (size_t)N_EDGES * 4;
  float* deg4    = (float*)(base + off); off += (size_t)4 * N_NODES * 4;
  int*  cursor   = (int*)(base + off);  off += (size_t)N_NODES * 4;
  int*  partial  = (int*)(base + off);  off += (size_t)N_NODES * 4;
  int*  blocksum = (int*)(base + off);  off += 512;
  int*  blockoff = (int*)(base + off);  off += 512;
  float* rdi     = (float*)(base + off); off += (size_t)N_NODES * 4;
  const size_t REQ1 = off;
  float* gsbuf   = (float*)(base + off); off += (size_t)N_NODES * DE * 4;
  float* csc     = (float*)(base + off); off += (size_t)N_NODES * 4;
  float* wcombo  = (float*)(base + off); off += (size_t)D * DE * 4;
  float* blbe    = (float*)(base + off); off += 512;
  const size_t REQ2 = off;
  int tier = (ws_size >= REQ2) ? 2 : (ws_size >= REQ1) ? 1 : 0;
  if (tier == 0) {
    // drop xh, shift remaining arrays down
    off = (size_t)N_EDGES * 16;
    pos      = (int*)(base + off);  off += (size_t)N_EDGES * 4;
    deg4     = (float*)(base + off); off += (size_t)4 * N_NODES * 4;
    cursor   = (int*)(base + off);  off += (size_t)N_NODES * 4;
    partial  = (int*)(base + off);  off += (size_t)N_NODES * 4;
    blocksum = (int*)(base + off);  off += 512;
    blockoff = (int*)(base + off);  off += 512;
    rdi      = (float*)(base + off); off += (size_t)N_NODES * 4;
    xh       = nullptr;
  }

  hipLaunchKernelGGL(init_kernel, dim3((5 * N_NODES + 255) / 256), dim3(256),
                     0, stream, (int*)deg4);
  hipLaunchKernelGGL(pre_kernel,
                     dim3(tier ? POS_BLOCKS + XH_BLOCKS : POS_BLOCKS),
                     dim3(256), 0, stream, (const int4*)el, cursor, (int2*)pos,
                     (const float4*)x, (uint4*)xh);
  hipLaunchKernelGGL(scan1_kernel, dim3(N_CHUNKS), dim3(256), 0, stream,
                     cursor, partial, blocksum);
  hipLaunchKernelGGL(scan2_kernel, dim3(1), dim3(128), 0, stream, blocksum,
                     blockoff);
  hipLaunchKernelGGL(place_kernel, dim3((N_EDGES / 2 + 255) / 256), dim3(256),
                     0, stream, (const int4*)el, (const float2*)ew,
                     (const int2*)pos, partial, blockoff, deg4, rec);
  hipLaunchKernelGGL(rdi_kernel, dim3((N_NODES + 255) / 256), dim3(256), 0,
                     stream, deg4, rdi);
  if (tier == 2) {
    hipLaunchKernelGGL(combo_kernel, dim3(16), dim3(256), 0, stream, W_lin,
                       W_edge, b_edge, wcombo, blbe);
    hipLaunchKernelGGL((gather_fused_kernel<true, false>),
                       dim3((N_NODES + 3) / 4), dim3(256), 0, stream, x, xh,
                       ef, partial, blockoff, cursor, rec, rdi, W_edge,
                       b_edge, gsbuf, csc, outp);
    hipLaunchKernelGGL(gemm2_mfma_kernel<true>, dim3((N_NODES + 127) / 128),
                       dim3(256), 0, stream, W_lin, b_lin, wcombo, blbe,
                       gsbuf, csc, outp);
  } else if (tier == 1) {
    hipLaunchKernelGGL((gather_fused_kernel<true, true>),
                       dim3((N_NODES + 3) / 4), dim3(256), 0, stream, x, xh,
                       ef, partial, blockoff, cursor, rec, rdi, W_edge,
                       b_edge, (float*)nullptr, (float*)nullptr, outp);
    hipLaunchKernelGGL(gemm2_mfma_kernel<false>, dim3((N_NODES + 127) / 128),
                       dim3(256), 0, stream, W_lin, b_lin, (const float*)nullptr,
                       (const float*)nullptr, (const float*)nullptr,
                       (const float*)nullptr, outp);
  } else {
    hipLaunchKernelGGL((gather_fused_kernel<false, true>),
                       dim3((N_NODES + 3) / 4), dim3(256), 0, stream, x, xh,
                       ef, partial, blockoff, cursor, rec, rdi, W_edge,
                       b_edge, (float*)nullptr, (float*)nullptr, outp);
    hipLaunchKernelGGL(gemm2_mfma_kernel<false>, dim3((N_NODES + 127) / 128),
                       dim3(256), 0, stream, W_lin, b_lin, (const float*)nullptr,
                       (const float*)nullptr, (const float*)nullptr,
                       (const float*)nullptr, outp);
  }
}

// Round 18
// 332.299 us; speedup vs baseline: 1.3035x; 1.0302x over previous
//
#include <hip/hip_runtime.h>

#define N_NODES 100000
#define N_EDGES 1600000
#define D 128
#define DE 32
#define SCAN_CHUNK 1024
#define N_CHUNKS ((N_NODES + SCAN_CHUNK - 1) / SCAN_CHUNK)  // 98
#define POS_BLOCKS (N_EDGES / 2 / 256)                      // 3125
#define XH_BLOCKS (N_NODES * D / 8 / 256)                   // 6250

typedef int v4i __attribute__((ext_vector_type(4)));     // nt-load-legal int4
typedef __attribute__((ext_vector_type(8))) short bf16x8;  // 8 bf16 = 4 VGPR
typedef __attribute__((ext_vector_type(4))) float f32x4;

// Algebra (R17): out = relu( A' @ Wl^T + gs @ (Wl@We)^T + csc*(Wl@be) + bl )
//   A' = rdo*(raw + rdi*x), gs = rdo*g, csc = rdo*wsv.
// R18: A' handed off as packed bf16 (ah) — numerically identical to gemm2's
// own staging quantization, but saves 25.6MB write + 25.6MB read.
//
// bf16: x gathered as bf16 (R9); GEMM inputs bf16 (R16). absmax 0.0039 vs
// 0.019 threshold. R11: no scalar-pipe rec. R14: don't bf16 one-shot ef.
// R15: don't pre-materialize ew*rdi (latency-hidden already).

__device__ inline float bflo(unsigned u) {
  return __uint_as_float(u << 16);
}
__device__ inline float bfhi(unsigned u) {
  return __uint_as_float(u & 0xFFFF0000u);
}
__device__ inline unsigned pk_bf2(float lo, float hi) {
  unsigned a = __float_as_uint(lo), b = __float_as_uint(hi);
  a = (a + 0x7FFFu + ((a >> 16) & 1)) >> 16;  // RNE
  b = (b + 0x7FFFu + ((b >> 16) & 1)) >> 16;
  return a | (b << 16);
}

// ---------------------------------------------------------------------------
// K1: zero deg replicas + cursor (contiguous 5N region).
__global__ __launch_bounds__(256) void init_kernel(int* __restrict__ z) {
  int idx = blockIdx.x * 256 + threadIdx.x;
  if (idx < 5 * N_NODES) z[idx] = 0;
}

// ---------------------------------------------------------------------------
// K2 (fused): blocks [0,POS_BLOCKS) do per-edge cursor atomics (2 edges/thr);
// remaining blocks convert x -> bf16 table xh (BW work overlaps atomic work).
__global__ __launch_bounds__(256) void pre_kernel(
    const int4* __restrict__ el2, int* __restrict__ cursor,
    int2* __restrict__ pos2, const float4* __restrict__ x4,
    uint4* __restrict__ xh4) {
  int b = blockIdx.x;
  if (b < POS_BLOCKS) {
    int i = b * 256 + threadIdx.x;  // edge-pair index
    if (i >= N_EDGES / 2) return;
    int4 e = el2[i];
    int2 p;
    p.x = atomicAdd(&cursor[e.y], 1);
    p.y = atomicAdd(&cursor[e.w], 1);
    pos2[i] = p;
  } else {
    int i = (b - POS_BLOCKS) * 256 + threadIdx.x;
    if (i >= N_NODES * D / 8) return;
    float4 f0 = x4[2 * i], f1 = x4[2 * i + 1];
    uint4 o;
    o.x = pk_bf2(f0.x, f0.y);
    o.y = pk_bf2(f0.z, f0.w);
    o.z = pk_bf2(f1.x, f1.y);
    o.w = pk_bf2(f1.z, f1.w);
    xh4[i] = o;
  }
}

// ---------------------------------------------------------------------------
// K3a: per-1024-chunk exclusive scan of counts(=cursor) -> partial, totals.
__global__ __launch_bounds__(256) void scan1_kernel(
    const int* __restrict__ counts, int* __restrict__ partial,
    int* __restrict__ blocksum) {
  __shared__ int lds[256];
  int t = threadIdx.x;
  int base = blockIdx.x * SCAN_CHUNK + t * 4;
  int c[4];
  int s = 0;
#pragma unroll
  for (int k = 0; k < 4; k++) {
    c[k] = (base + k < N_NODES) ? counts[base + k] : 0;
    s += c[k];
  }
  lds[t] = s;
  __syncthreads();
  for (int off = 1; off < 256; off <<= 1) {
    int tmp = (t >= off) ? lds[t - off] : 0;
    __syncthreads();
    lds[t] += tmp;
    __syncthreads();
  }
  int run = lds[t] - s;
#pragma unroll
  for (int k = 0; k < 4; k++) {
    int v = base + k;
    if (v < N_NODES) partial[v] = run;
    run += c[k];
  }
  if (t == 255) blocksum[blockIdx.x] = lds[255];
}

// ---------------------------------------------------------------------------
// K3b: exclusive scan of the 98 chunk totals.
__global__ __launch_bounds__(128) void scan2_kernel(
    const int* __restrict__ blocksum, int* __restrict__ blockoff) {
  __shared__ int lds[128];
  int t = threadIdx.x;
  int v = (t < N_CHUNKS) ? blocksum[t] : 0;
  lds[t] = v;
  __syncthreads();
  for (int off = 1; off < 128; off <<= 1) {
    int tmp = (t >= off) ? lds[t - off] : 0;
    __syncthreads();
    lds[t] += tmp;
    __syncthreads();
  }
  if (t < N_CHUNKS) blockoff[t] = lds[t] - v;
}

// ---------------------------------------------------------------------------
// K4: place 16B AoS records {src, eid, ew, 0} at start[dst]+pos + deg_in
// replica atomics.
__global__ __launch_bounds__(256) void place_kernel(
    const int4* __restrict__ el2, const float2* __restrict__ ew2,
    const int2* __restrict__ pos2, const int* __restrict__ partial,
    const int* __restrict__ blockoff, float* __restrict__ deg4,
    int4* __restrict__ rec) {
  int i = blockIdx.x * 256 + threadIdx.x;  // edge-pair index
  if (i >= N_EDGES / 2) return;
  int4 e = el2[i];
  float2 w = ew2[i];
  int2 p = pos2[i];
  int r0 = (threadIdx.x & 3) * N_NODES;
  atomicAdd(&deg4[r0 + e.x], w.x);
  atomicAdd(&deg4[r0 + e.z], w.y);
  int4 rA, rB;
  rA.x = e.x; rA.y = 2 * i;     rA.z = __float_as_int(w.x); rA.w = 0;
  rB.x = e.z; rB.y = 2 * i + 1; rB.z = __float_as_int(w.y); rB.w = 0;
  rec[partial[e.y] + blockoff[e.y >> 10] + p.x] = rA;
  rec[partial[e.w] + blockoff[e.w >> 10] + p.y] = rB;
}

// ---------------------------------------------------------------------------
// K5: finalize rdi = rsqrt(1 + sum of 4 deg replicas).
__global__ __launch_bounds__(256) void rdi_kernel(
    const float* __restrict__ deg4, float* __restrict__ rdi) {
  int v = blockIdx.x * 256 + threadIdx.x;
  if (v >= N_NODES) return;
  rdi[v] = rsqrtf(1.f + deg4[v] + deg4[N_NODES + v] + deg4[2 * N_NODES + v] +
                  deg4[3 * N_NODES + v]);
}

// ---------------------------------------------------------------------------
// K5c: Wcombo = W_lin @ W_edge (128x32); blbe = W_lin @ b_edge (128).
__global__ __launch_bounds__(256) void combo_kernel(
    const float* __restrict__ W_lin, const float* __restrict__ W_edge,
    const float* __restrict__ b_edge, float* __restrict__ wcombo,
    float* __restrict__ blbe) {
  int idx = blockIdx.x * 256 + threadIdx.x;
  int j = idx >> 5, k = idx & 31;
  float s = 0.f;
#pragma unroll 8
  for (int d = 0; d < D; ++d) s += W_lin[j * D + d] * W_edge[d * DE + k];
  wcombo[j * DE + k] = s;
  if (blockIdx.x == 0 && threadIdx.x < D) {
    int jj = threadIdx.x;
    float b = 0.f;
#pragma unroll 8
    for (int d = 0; d < D; ++d) b += W_lin[jj * D + d] * b_edge[d];
    blbe[jj] = b;
  }
}

// ---------------------------------------------------------------------------
// K6: single-pass fused gather. One wave per node, 8 edges/iter, nt rec
// loads + shfl broadcasts; lane l owns dims 2l,2l+1 (u32 = 2xbf16 per row).
// FUSEWE=true: legacy W_edge epilogue (fallback tiers), f32 out.
// FUSEWE=false (R17/R18): thin epilogue — ONE u32 store of packed
// bf16 A' = rdo*(raw + rdi*x) into ah; g/wsv -> gs/csc for the MFMA GEMM.
template <bool XH16, bool FUSEWE>
__global__ __launch_bounds__(256) void gather_fused_kernel(
    const float* __restrict__ x, const ushort* __restrict__ xh,
    const float* __restrict__ ef, const int* __restrict__ partial,
    const int* __restrict__ blockoff, const int* __restrict__ counts,
    const int4* __restrict__ rec, const float* __restrict__ rdi,
    const float* __restrict__ W_edge, const float* __restrict__ b_edge,
    float* __restrict__ gs, float* __restrict__ csc,
    unsigned* __restrict__ ah, float* __restrict__ out) {
  __shared__ __align__(16) float we[FUSEWE ? 128 * 36 : 4];
  __shared__ float beS[FUSEWE ? 128 : 4];
  int t = threadIdx.x;
  if (FUSEWE) {
#pragma unroll
    for (int i = 0; i < 4; ++i) {  // 1024 float4 / 256 threads
      int f = t + i * 256;
      int r = f >> 3, kq = f & 7;
      *(float4*)&we[r * 36 + 4 * kq] =
          *(const float4*)&W_edge[r * DE + 4 * kq];
    }
    if (t < 128) beS[t] = b_edge[t];
    __syncthreads();
  }

  int wid = t >> 6, lane = t & 63;
  int v = blockIdx.x * 4 + wid;
  if (v >= N_NODES) return;
  int start = partial[v] + blockoff[v >> 10];
  int cnt = counts[v];
  int lane31 = lane & 31;
  bool lowhalf = lane < 32;

  float A0 = 0.f, A1 = 0.f, B0 = 0.f, B1 = 0.f;
  float C0 = 0.f, C1 = 0.f, E0 = 0.f, E1 = 0.f;
  float ga = 0.f, gb = 0.f, gc = 0.f, gd = 0.f, dsum = 0.f, wsv = 0.f;

#define EFLOAD(eid) __builtin_nontemporal_load(&ef[(size_t)(eid)*DE + lane31])

  for (int base = 0; base < cnt; base += 64) {
    int nb = cnt - base;
    if (nb > 64) nb = 64;
    int s_l = 0, e_l = 0;
    float w_l = 0.f;
    if (lane < nb) {
      v4i rv = __builtin_nontemporal_load(
          (const v4i*)&rec[start + base + lane]);
      s_l = rv.x;
      e_l = rv.y;
      float wraw = __int_as_float(rv.z);
      w_l = wraw * rdi[s_l];
      dsum += wraw;
      wsv += w_l;
    }
    int i = 0;
    for (; i + 8 <= nb; i += 8) {
      int s0 = __shfl(s_l, i + 0), s1 = __shfl(s_l, i + 1);
      int s2 = __shfl(s_l, i + 2), s3 = __shfl(s_l, i + 3);
      int s4 = __shfl(s_l, i + 4), s5 = __shfl(s_l, i + 5);
      int s6 = __shfl(s_l, i + 6), s7 = __shfl(s_l, i + 7);
      float w0 = __shfl(w_l, i + 0), w1 = __shfl(w_l, i + 1);
      float w2 = __shfl(w_l, i + 2), w3 = __shfl(w_l, i + 3);
      float w4 = __shfl(w_l, i + 4), w5 = __shfl(w_l, i + 5);
      float w6 = __shfl(w_l, i + 6), w7 = __shfl(w_l, i + 7);
      int hh = lane >> 5;
      int eA = __shfl(e_l, i + 0 + hh), eB = __shfl(e_l, i + 2 + hh);
      int eC = __shfl(e_l, i + 4 + hh), eD = __shfl(e_l, i + 6 + hh);
      float wA = lowhalf ? w0 : w1, wB = lowhalf ? w2 : w3;
      float wC = lowhalf ? w4 : w5, wD = lowhalf ? w6 : w7;
      ga = fmaf(wA, EFLOAD(eA), ga);
      gb = fmaf(wB, EFLOAD(eB), gb);
      gc = fmaf(wC, EFLOAD(eC), gc);
      gd = fmaf(wD, EFLOAD(eD), gd);
      if (XH16) {
        unsigned u0 = ((const unsigned*)(xh + (size_t)s0 * D))[lane];
        unsigned u1 = ((const unsigned*)(xh + (size_t)s1 * D))[lane];
        unsigned u2 = ((const unsigned*)(xh + (size_t)s2 * D))[lane];
        unsigned u3 = ((const unsigned*)(xh + (size_t)s3 * D))[lane];
        unsigned u4 = ((const unsigned*)(xh + (size_t)s4 * D))[lane];
        unsigned u5 = ((const unsigned*)(xh + (size_t)s5 * D))[lane];
        unsigned u6 = ((const unsigned*)(xh + (size_t)s6 * D))[lane];
        unsigned u7 = ((const unsigned*)(xh + (size_t)s7 * D))[lane];
        A0 = fmaf(w0, bflo(u0), A0); A1 = fmaf(w0, bfhi(u0), A1);
        B0 = fmaf(w1, bflo(u1), B0); B1 = fmaf(w1, bfhi(u1), B1);
        C0 = fmaf(w2, bflo(u2), C0); C1 = fmaf(w2, bfhi(u2), C1);
        E0 = fmaf(w3, bflo(u3), E0); E1 = fmaf(w3, bfhi(u3), E1);
        A0 = fmaf(w4, bflo(u4), A0); A1 = fmaf(w4, bfhi(u4), A1);
        B0 = fmaf(w5, bflo(u5), B0); B1 = fmaf(w5, bfhi(u5), B1);
        C0 = fmaf(w6, bflo(u6), C0); C1 = fmaf(w6, bfhi(u6), C1);
        E0 = fmaf(w7, bflo(u7), E0); E1 = fmaf(w7, bfhi(u7), E1);
      } else {
        float2 u0 = ((const float2*)(x + (size_t)s0 * D))[lane];
        float2 u1 = ((const float2*)(x + (size_t)s1 * D))[lane];
        float2 u2 = ((const float2*)(x + (size_t)s2 * D))[lane];
        float2 u3 = ((const float2*)(x + (size_t)s3 * D))[lane];
        float2 u4 = ((const float2*)(x + (size_t)s4 * D))[lane];
        float2 u5 = ((const float2*)(x + (size_t)s5 * D))[lane];
        float2 u6 = ((const float2*)(x + (size_t)s6 * D))[lane];
        float2 u7 = ((const float2*)(x + (size_t)s7 * D))[lane];
        A0 = fmaf(w0, u0.x, A0); A1 = fmaf(w0, u0.y, A1);
        B0 = fmaf(w1, u1.x, B0); B1 = fmaf(w1, u1.y, B1);
        C0 = fmaf(w2, u2.x, C0); C1 = fmaf(w2, u2.y, C1);
        E0 = fmaf(w3, u3.x, E0); E1 = fmaf(w3, u3.y, E1);
        A0 = fmaf(w4, u4.x, A0); A1 = fmaf(w4, u4.y, A1);
        B0 = fmaf(w5, u5.x, B0); B1 = fmaf(w5, u5.y, B1);
        C0 = fmaf(w6, u6.x, C0); C1 = fmaf(w6, u6.y, C1);
        E0 = fmaf(w7, u7.x, E0); E1 = fmaf(w7, u7.y, E1);
      }
    }
    for (; i + 2 <= nb; i += 2) {
      int s0 = __shfl(s_l, i), s1 = __shfl(s_l, i + 1);
      float w0 = __shfl(w_l, i), w1 = __shfl(w_l, i + 1);
      int eE = __shfl(e_l, i + (lane >> 5));
      float wE = lowhalf ? w0 : w1;
      ga = fmaf(wE, EFLOAD(eE), ga);
      if (XH16) {
        unsigned u0 = ((const unsigned*)(xh + (size_t)s0 * D))[lane];
        unsigned u1 = ((const unsigned*)(xh + (size_t)s1 * D))[lane];
        A0 = fmaf(w0, bflo(u0), A0); A1 = fmaf(w0, bfhi(u0), A1);
        B0 = fmaf(w1, bflo(u1), B0); B1 = fmaf(w1, bfhi(u1), B1);
      } else {
        float2 u0 = ((const float2*)(x + (size_t)s0 * D))[lane];
        float2 u1 = ((const float2*)(x + (size_t)s1 * D))[lane];
        A0 = fmaf(w0, u0.x, A0); A1 = fmaf(w0, u0.y, A1);
        B0 = fmaf(w1, u1.x, B0); B1 = fmaf(w1, u1.y, B1);
      }
    }
    if (i < nb) {
      int s0 = __shfl(s_l, i);
      float w0 = __shfl(w_l, i);
      int eA = __shfl(e_l, i);
      if (lowhalf) ga = fmaf(w0, EFLOAD(eA), ga);
      if (XH16) {
        unsigned u0 = ((const unsigned*)(xh + (size_t)s0 * D))[lane];
        A0 = fmaf(w0, bflo(u0), A0);
        A1 = fmaf(w0, bfhi(u0), A1);
      } else {
        float2 u0 = ((const float2*)(x + (size_t)s0 * D))[lane];
        A0 = fmaf(w0, u0.x, A0);
        A1 = fmaf(w0, u0.y, A1);
      }
    }
  }
#undef EFLOAD
  float a0 = (A0 + B0) + (C0 + E0);  // dim 2*lane
  float a1 = (A1 + B1) + (C1 + E1);  // dim 2*lane+1
#pragma unroll
  for (int off = 32; off; off >>= 1) {
    dsum += __shfl_xor(dsum, off);
    wsv += __shfl_xor(wsv, off);
  }
  float rdo = rsqrtf(1.f + dsum);
  float gk = (ga + gb) + (gc + gd);
  gk += __shfl(gk, (lane + 32) & 63);  // lanes 0..31 hold full g_k

  size_t ro = (size_t)v * D;
  float rdiv = rdi[v];

  if (!FUSEWE) {
    // R18 thin epilogue: pack A' = rdo*(raw + rdi*x) as 2xbf16, one store.
    // (Identical quantization to gemm2's old staging — zero added error.)
    float xs0, xs1;
    if (XH16) {
      unsigned u = ((const unsigned*)(xh + ro))[lane];
      xs0 = bflo(u);
      xs1 = bfhi(u);
    } else {
      float2 u = ((const float2*)(x + ro))[lane];
      xs0 = u.x;
      xs1 = u.y;
    }
    ah[ro / 2 + lane] =
        pk_bf2(rdo * (a0 + rdiv * xs0), rdo * (a1 + rdiv * xs1));
    if (lowhalf) gs[(size_t)v * DE + lane] = rdo * gk;
    if (lane == 0) csc[v] = rdo * wsv;
    return;
  }

  // legacy epilogue (fallback tiers): lane transpose + W_edge matvec
  int half = lane >> 1;
  float v0 = __shfl(a0, half), v1 = __shfl(a1, half);
  float accLo = (lane & 1) ? v1 : v0;  // dim = lane
  float q0 = __shfl(a0, 32 + half), q1 = __shfl(a1, 32 + half);
  float accHi = (lane & 1) ? q1 : q0;  // dim = lane + 64

  float xs0, xs1;
  if (XH16) {
    xs0 = __uint_as_float((unsigned)xh[ro + lane] << 16);
    xs1 = __uint_as_float((unsigned)xh[ro + lane + 64] << 16);
  } else {
    xs0 = x[ro + lane];
    xs1 = x[ro + lane + 64];
  }
  float s0 = accLo + rdiv * xs0 + wsv * beS[lane];
  float s1 = accHi + rdiv * xs1 + wsv * beS[lane + 64];
#pragma unroll
  for (int kq = 0; kq < 8; ++kq) {
    float4 w0 = *(const float4*)&we[lane * 36 + 4 * kq];
    float4 w1 = *(const float4*)&we[(lane + 64) * 36 + 4 * kq];
    float g0 = __shfl(gk, 4 * kq);
    float g1 = __shfl(gk, 4 * kq + 1);
    float g2 = __shfl(gk, 4 * kq + 2);
    float g3 = __shfl(gk, 4 * kq + 3);
    s0 += g0 * w0.x + g1 * w0.y + g2 * w0.z + g3 * w0.w;
    s1 += g0 * w1.x + g1 * w1.y + g2 * w1.z + g3 * w1.w;
  }
  out[ro + lane] = rdo * s0;
  out[ro + lane + 64] = rdo * s1;
}

// ---------------------------------------------------------------------------
// K7: MFMA GEMM, bf16 inputs, f32 accumulate.
// EXT=false: out = relu(out @ Wl^T + bl)                (A from out, f32)
// EXT=true : out = relu(ah @ Wl^T + gs @ Wcombo^T + csc*blbe + bl)
//            (A from ah, already bf16 — no staging conversion; K=160)
template <bool EXT>
__global__ __launch_bounds__(256) void gemm2_mfma_kernel(
    const float* __restrict__ W_lin, const float* __restrict__ b_lin,
    const float* __restrict__ wcombo, const float* __restrict__ blbe,
    const float* __restrict__ gs, const float* __restrict__ csc,
    const unsigned* __restrict__ ah, float* __restrict__ out) {
  __shared__ __align__(16) ushort Asb[128 * 40];   // 10240 B
  __shared__ __align__(16) ushort Wsb[128 * 132];  // 33792 B
  __shared__ __align__(16) ushort Csb[128 * 36];   //  9216 B
  int t = threadIdx.x;
  int vbase = blockIdx.x * 128;

  // stage W_lin once (4096 float4 / 256 threads)
#pragma unroll
  for (int i = 0; i < 16; ++i) {
    int idx = t + i * 256;
    int r = idx >> 5;
    int c = (idx & 31) * 4;
    float4 f = *(const float4*)&W_lin[r * D + c];
    uint2 u;
    u.x = pk_bf2(f.x, f.y);
    u.y = pk_bf2(f.z, f.w);
    *(uint2*)&Wsb[r * 132 + c] = u;
  }
  if (EXT) {
#pragma unroll
    for (int i = 0; i < 4; ++i) {
      int idx = t + i * 256;  // 0..1023
      int r = idx >> 3;
      int c = (idx & 7) * 4;
      float4 f = *(const float4*)&wcombo[r * DE + c];
      uint2 u;
      u.x = pk_bf2(f.x, f.y);
      u.y = pk_bf2(f.z, f.w);
      *(uint2*)&Csb[r * 36 + c] = u;
    }
  }

  int lane = t & 63, w = t >> 6;
  int l15 = lane & 15, kg = lane >> 4;
  f32x4 acc[2][8] = {};

  const int KSTEPS = EXT ? 5 : 4;
  for (int ks = 0; ks < KSTEPS; ++ks) {
    __syncthreads();  // protects Asb reuse (and W staging on first iter)
#pragma unroll
    for (int i = 0; i < 4; ++i) {
      int idx = t + i * 256;  // 0..1023
      int r = idx >> 3;
      int c = (idx & 7) * 4;
      uint2 u = make_uint2(0, 0);
      if (vbase + r < N_NODES) {
        if (EXT) {
          if (ks < 4) {
            // ah already bf16-packed: direct copy, no conversion
            u = *(const uint2*)&ah[((size_t)(vbase + r) * D + ks * 32 + c) / 2];
          } else {
            float4 f = *(const float4*)&gs[(size_t)(vbase + r) * DE + c];
            u.x = pk_bf2(f.x, f.y);
            u.y = pk_bf2(f.z, f.w);
          }
        } else {
          float4 f = *(const float4*)&out[(size_t)(vbase + r) * D + ks * 32 + c];
          u.x = pk_bf2(f.x, f.y);
          u.y = pk_bf2(f.z, f.w);
        }
      }
      *(uint2*)&Asb[r * 40 + c] = u;
    }
    __syncthreads();
    bf16x8 a0 = *(const bf16x8*)&Asb[(w * 32 + l15) * 40 + kg * 8];
    bf16x8 a1 = *(const bf16x8*)&Asb[(w * 32 + 16 + l15) * 40 + kg * 8];
#pragma unroll
    for (int nt = 0; nt < 8; ++nt) {
      uint2 q0, q1;
      if (!EXT || ks < 4) {
        const ushort* bp = &Wsb[(nt * 16 + l15) * 132 + ks * 32 + kg * 8];
        q0 = *(const uint2*)bp;
        q1 = *(const uint2*)(bp + 4);
      } else {
        const ushort* bp = &Csb[(nt * 16 + l15) * 36 + kg * 8];
        q0 = *(const uint2*)bp;
        q1 = *(const uint2*)(bp + 4);
      }
      uint4 bu = make_uint4(q0.x, q0.y, q1.x, q1.y);
      bf16x8 bf = *(bf16x8*)&bu;
      acc[0][nt] =
          __builtin_amdgcn_mfma_f32_16x16x32_bf16(a0, bf, acc[0][nt], 0, 0, 0);
      acc[1][nt] =
          __builtin_amdgcn_mfma_f32_16x16x32_bf16(a1, bf, acc[1][nt], 0, 0, 0);
    }
  }

  // epilogue: bias (+ rank-1 csc*blbe if EXT) + relu, store f32
#pragma unroll
  for (int nt = 0; nt < 8; ++nt) {
    int col = nt * 16 + l15;
    float bl = b_lin[col];
    float bb = EXT ? blbe[col] : 0.f;
#pragma unroll
    for (int mt = 0; mt < 2; ++mt) {
#pragma unroll
      for (int j = 0; j < 4; ++j) {
        int row = vbase + w * 32 + mt * 16 + kg * 4 + j;
        if (row < N_NODES) {
          float val = acc[mt][nt][j] + bl;
          if (EXT) val += csc[row] * bb;
          out[(size_t)row * D + col] = fmaxf(val, 0.f);
        }
      }
    }
  }
}

// ---------------------------------------------------------------------------
extern "C" void kernel_launch(void* const* d_in, const int* in_sizes, int n_in,
                              void* d_out, int out_size, void* d_ws,
                              size_t ws_size, hipStream_t stream) {
  const float* x      = (const float*)d_in[0];
  const int*   el     = (const int*)d_in[1];
  const float* ew     = (const float*)d_in[2];
  const float* ef     = (const float*)d_in[3];
  const float* W_lin  = (const float*)d_in[4];
  const float* b_lin  = (const float*)d_in[5];
  const float* W_edge = (const float*)d_in[6];
  const float* b_edge = (const float*)d_in[7];

  float* outp = (float*)d_out;

  // tiers: T2 (~99.2MB) bf16-A' handoff + K=160 GEMM; T1 (~60.4MB) = R16;
  // T0 (~34.8MB) f32 gather + K=128 GEMM.
  char* base = (char*)d_ws;
  size_t off = 0;
  int4* rec      = (int4*)(base + off); off += (size_t)N_EDGES * 16;
  ushort* xh     = (ushort*)(base + off); off += (size_t)N_NODES * D * 2;
  int*  pos      = (int*)(base + off);  off += (size_t)N_EDGES * 4;
  float* deg4    = (float*)(base + off); off += (size_t)4 * N_NODES * 4;
  int*  cursor   = (int*)(base + off);  off += (size_t)N_NODES * 4;
  int*  partial  = (int*)(base + off);  off += (size_t)N_NODES * 4;
  int*  blocksum = (int*)(base + off);  off += 512;
  int*  blockoff = (int*)(base + off);  off += 512;
  float* rdi     = (float*)(base + off); off += (size_t)N_NODES * 4;
  const size_t REQ1 = off;
  unsigned* ah   = (unsigned*)(base + off); off += (size_t)N_NODES * D * 2;
  float* gsbuf   = (float*)(base + off); off += (size_t)N_NODES * DE * 4;
  float* csc     = (float*)(base + off); off += (size_t)N_NODES * 4;
  float* wcombo  = (float*)(base + off); off += (size_t)D * DE * 4;
  float* blbe    = (float*)(base + off); off += 512;
  const size_t REQ2 = off;
  int tier = (ws_size >= REQ2) ? 2 : (ws_size >= REQ1) ? 1 : 0;
  if (tier == 0) {
    // drop xh, shift remaining arrays down
    off = (size_t)N_EDGES * 16;
    pos      = (int*)(base + off);  off += (size_t)N_EDGES * 4;
    deg4     = (float*)(base + off); off += (size_t)4 * N_NODES * 4;
    cursor   = (int*)(base + off);  off += (size_t)N_NODES * 4;
    partial  = (int*)(base + off);  off += (size_t)N_NODES * 4;
    blocksum = (int*)(base + off);  off += 512;
    blockoff = (int*)(base + off);  off += 512;
    rdi      = (float*)(base + off); off += (size_t)N_NODES * 4;
    xh       = nullptr;
  }

  hipLaunchKernelGGL(init_kernel, dim3((5 * N_NODES + 255) / 256), dim3(256),
                     0, stream, (int*)deg4);
  hipLaunchKernelGGL(pre_kernel,
                     dim3(tier ? POS_BLOCKS + XH_BLOCKS : POS_BLOCKS),
                     dim3(256), 0, stream, (const int4*)el, cursor, (int2*)pos,
                     (const float4*)x, (uint4*)xh);
  hipLaunchKernelGGL(scan1_kernel, dim3(N_CHUNKS), dim3(256), 0, stream,
                     cursor, partial, blocksum);
  hipLaunchKernelGGL(scan2_kernel, dim3(1), dim3(128), 0, stream, blocksum,
                     blockoff);
  hipLaunchKernelGGL(place_kernel, dim3((N_EDGES / 2 + 255) / 256), dim3(256),
                     0, stream, (const int4*)el, (const float2*)ew,
                     (const int2*)pos, partial, blockoff, deg4, rec);
  hipLaunchKernelGGL(rdi_kernel, dim3((N_NODES + 255) / 256), dim3(256), 0,
                     stream, deg4, rdi);
  if (tier == 2) {
    hipLaunchKernelGGL(combo_kernel, dim3(16), dim3(256), 0, stream, W_lin,
                       W_edge, b_edge, wcombo, blbe);
    hipLaunchKernelGGL((gather_fused_kernel<true, false>),
                       dim3((N_NODES + 3) / 4), dim3(256), 0, stream, x, xh,
                       ef, partial, blockoff, cursor, rec, rdi, W_edge,
                       b_edge, gsbuf, csc, ah, outp);
    hipLaunchKernelGGL(gemm2_mfma_kernel<true>, dim3((N_NODES + 127) / 128),
                       dim3(256), 0, stream, W_lin, b_lin, wcombo, blbe,
                       gsbuf, csc, ah, outp);
  } else if (tier == 1) {
    hipLaunchKernelGGL((gather_fused_kernel<true, true>),
                       dim3((N_NODES + 3) / 4), dim3(256), 0, stream, x, xh,
                       ef, partial, blockoff, cursor, rec, rdi, W_edge,
                       b_edge, (float*)nullptr, (float*)nullptr,
                       (unsigned*)nullptr, outp);
    hipLaunchKernelGGL(gemm2_mfma_kernel<false>, dim3((N_NODES + 127) / 128),
                       dim3(256), 0, stream, W_lin, b_lin,
                       (const float*)nullptr, (const float*)nullptr,
                       (const float*)nullptr, (const float*)nullptr,
                       (const unsigned*)nullptr, outp);
  } else {
    hipLaunchKernelGGL((gather_fused_kernel<false, true>),
                       dim3((N_NODES + 3) / 4), dim3(256), 0, stream, x, xh,
                       ef, partial, blockoff, cursor, rec, rdi, W_edge,
                       b_edge, (float*)nullptr, (float*)nullptr,
                       (unsigned*)nullptr, outp);
    hipLaunchKernelGGL(gemm2_mfma_kernel<false>, dim3((N_NODES + 127) / 128),
                       dim3(256), 0, stream, W_lin, b_lin,
                       (const float*)nullptr, (const float*)nullptr,
                       (const float*)nullptr, (const float*)nullptr,
                       (const unsigned*)nullptr, outp);
  }
}